// Round 1
// baseline (2459.094 us; speedup 1.0000x reference)
//
#include <hip/hip_runtime.h>
#include <hip/hip_bf16.h>

// Shapes
// B=64 S=32 H=40 W=64 ; conv1: 1->32 (20x32) ; conv2: 32->64 (10x16) ; conv3: 64->32 (5x8)
// SENS=1283 UNITS=48 MOTOR=4 NA=2 UNFOLDS=6

constexpr int NSENS = 1283 * 48;      // 61584
constexpr int NREC  = 48 * 48;        // 2304
constexpr int SSTRIDE = 61648;        // padded (+64) so lanes u in [48,64) read in-bounds
constexpr int RSTRIDE = 2368;

constexpr long OFF_SEQ = 0;                       // 2048*1283 = 2627584 floats
constexpr long OFF_SW  = 2627584;                 // 4 arrays x SSTRIDE
constexpr long OFF_RW  = OFF_SW + 4L * SSTRIDE;   // 4 arrays x RSTRIDE
constexpr long OFF_CM  = OFF_RW + 4L * RSTRIDE;   // cm_t(64), gl(64), glv(64)
constexpr long OFF_WN  = OFF_CM + 192;            // 2048*48
constexpr long OFF_WD  = OFF_WN + 98304;          // 2048*48
// total = 3,080,448 floats = ~11.8 MiB of d_ws

__device__ __forceinline__ float sp_(float x) {
    // softplus, numerically stable (matches jax.nn.softplus)
    return fmaxf(x, 0.f) + log1pf(expf(-fabsf(x)));
}

// ---------------------------------------------------------------------------
// prep: fold params.  sigmoid(sigma*(x-mu)) = rcp(1 + exp2(A*x + Bc)),
// A = -sigma*log2e, Bc = sigma*mu*log2e.  sw = softplus(w)*mask, swe = sw*erev.
// ---------------------------------------------------------------------------
__global__ void prep_kernel(const float* __restrict__ sens_w, const float* __restrict__ sens_mu,
                            const float* __restrict__ sens_sigma, const float* __restrict__ sens_erev,
                            const int* __restrict__ sens_mask,
                            const float* __restrict__ rec_w, const float* __restrict__ rec_mu,
                            const float* __restrict__ rec_sigma, const float* __restrict__ rec_erev,
                            const int* __restrict__ rec_mask,
                            const float* __restrict__ gleak, const float* __restrict__ vleak,
                            const float* __restrict__ cm, float* __restrict__ ws) {
    const float L2E = 1.4426950408889634f;
    int i = blockIdx.x * 256 + threadIdx.x;
    if (i < NSENS) {
        float m  = sens_mask[i] ? 1.f : 0.f;
        float sw = sp_(sens_w[i]) * m;
        float sg = sens_sigma[i], mu = sens_mu[i];
        ws[OFF_SW + i]               = sw;
        ws[OFF_SW + SSTRIDE + i]     = sw * sens_erev[i];
        ws[OFF_SW + 2 * SSTRIDE + i] = -sg * L2E;
        ws[OFF_SW + 3 * SSTRIDE + i] = sg * mu * L2E;
    } else if (i < NSENS + NREC) {
        int j = i - NSENS;
        float m  = rec_mask[j] ? 1.f : 0.f;
        float sw = sp_(rec_w[j]) * m;
        float sg = rec_sigma[j], mu = rec_mu[j];
        ws[OFF_RW + j]               = sw;
        ws[OFF_RW + RSTRIDE + j]     = sw * rec_erev[j];
        ws[OFF_RW + 2 * RSTRIDE + j] = -sg * L2E;
        ws[OFF_RW + 3 * RSTRIDE + j] = sg * mu * L2E;
    } else if (i < NSENS + NREC + 48) {
        int u = i - (NSENS + NREC);
        float g = sp_(gleak[u]);
        ws[OFF_CM + u]        = sp_(cm[u]) * 6.f;   // cm_t = softplus(cm)*UNFOLDS
        ws[OFF_CM + 64 + u]   = g;
        ws[OFF_CM + 128 + u]  = g * vleak[u];
    }
}

// ---------------------------------------------------------------------------
// Fused CNN: one block per image (2048 blocks x 256 threads), all in LDS.
// LDS layout (floats):
//  phase A: imgp[41][65]=2665 @0 | c1p[8][21][33]=5544 @2665 | w2c[64][72]=4608 @8209
//           w1s 288 @12817 | b1s 32 @13105 | b2s 64 @13137
//  phase C: act2p[64][11][17]=11968 @0 | w3c[32][36]=1152 @11968 | b3s 32 @13216
// ---------------------------------------------------------------------------
#define O_IMG 0
#define O_C1P 2665
#define O_W2C 8209
#define O_W1S 12817
#define O_B1S 13105
#define O_B2S 13137
#define O_W3C 11968
#define O_B3S 13216
#define SM_SIZE 13248

__global__ __launch_bounds__(256, 3) void cnn_kernel(
    const float* __restrict__ depth, const float* __restrict__ relpos,
    const float* __restrict__ w1, const float* __restrict__ b1,
    const float* __restrict__ w2, const float* __restrict__ b2,
    const float* __restrict__ w3, const float* __restrict__ b3,
    float* __restrict__ seq) {
    __shared__ float sm[SM_SIZE];
    const int t = threadIdx.x;
    const int img = blockIdx.x;

    // zero padded imgp + c1p once (pads stay zero for all chunks)
    for (int l = t; l < O_C1P + 5544; l += 256) sm[l] = 0.f;
    __syncthreads();
    // stage image interior + small params
    for (int l = t; l < 2560; l += 256) {
        int h = l >> 6, w = l & 63;
        sm[O_IMG + (h + 1) * 65 + (w + 1)] = depth[img * 2560 + l];
    }
    for (int l = t; l < 288; l += 256) sm[O_W1S + l] = w1[l];
    if (t < 32) sm[O_B1S + t] = b1[t];
    if (t < 64) sm[O_B2S + t] = b2[t];
    if (t < 32) sm[O_B3S + t] = b3[t];
    __syncthreads();

    const int ocg  = t >> 5;       // 0..7 : output-channel group (8 oc each)
    const int lane = t & 31;
    const int ox   = lane & 15;    // 0..15
    const int oy0  = lane >> 4;    // 0..1 ; this thread's px: (oy0+2r, ox), r=0..4

    float acc[8][5];
#pragma unroll
    for (int a = 0; a < 8; ++a)
#pragma unroll
        for (int r = 0; r < 5; ++r) acc[a][r] = 0.f;

#pragma unroll 1
    for (int cc = 0; cc < 4; ++cc) {  // 4 chunks of 8 conv1 channels
        // conv1 chunk -> c1p interior
#pragma unroll 1
        for (int l = t; l < 5120; l += 256) {
            int cl = l / 640;
            int p  = l - cl * 640;
            int oyc = p >> 5, oxc = p & 31;
            int c = cc * 8 + cl;
            float a = sm[O_B1S + c];
#pragma unroll
            for (int ky = 0; ky < 3; ++ky)
#pragma unroll
                for (int kx = 0; kx < 3; ++kx)
                    a = fmaf(sm[O_W1S + c * 9 + ky * 3 + kx],
                             sm[O_IMG + (2 * oyc + ky) * 65 + (2 * oxc + kx)], a);
            sm[O_C1P + cl * 693 + (oyc + 1) * 33 + (oxc + 1)] = fmaxf(a, 0.f);
        }
        // stage w2 chunk: [64 oc][8 ic][9]
        for (int l = t; l < 4608; l += 256) {
            int oc = l / 72;
            int j  = l - oc * 72;
            sm[O_W2C + l] = w2[oc * 288 + cc * 72 + j];
        }
        __syncthreads();
        // conv2 accumulate (8 oc x 5 px per thread)
#pragma unroll
        for (int ky = 0; ky < 3; ++ky) {
#pragma unroll
            for (int kx = 0; kx < 3; ++kx) {
                const int ib = O_C1P + (2 * oy0 + ky) * 33 + (2 * ox + kx);
                const int wb = O_W2C + ocg * 8 * 72 + ky * 3 + kx;
#pragma unroll
                for (int ic = 0; ic < 8; ++ic) {
                    float x0 = sm[ib + ic * 693];
                    float x1 = sm[ib + ic * 693 + 132];
                    float x2 = sm[ib + ic * 693 + 264];
                    float x3 = sm[ib + ic * 693 + 396];
                    float x4 = sm[ib + ic * 693 + 528];
#pragma unroll
                    for (int r8 = 0; r8 < 8; ++r8) {
                        float w = sm[wb + r8 * 72 + ic * 9];
                        acc[r8][0] = fmaf(w, x0, acc[r8][0]);
                        acc[r8][1] = fmaf(w, x1, acc[r8][1]);
                        acc[r8][2] = fmaf(w, x2, acc[r8][2]);
                        acc[r8][3] = fmaf(w, x3, acc[r8][3]);
                        acc[r8][4] = fmaf(w, x4, acc[r8][4]);
                    }
                }
            }
        }
        __syncthreads();
    }

    // phase B: write act2 (bias+relu) into padded LDS
    for (int l = t; l < 11968; l += 256) sm[l] = 0.f;
    __syncthreads();
#pragma unroll
    for (int r8 = 0; r8 < 8; ++r8) {
        int oc = ocg * 8 + r8;
        float bias = sm[O_B2S + oc];
#pragma unroll
        for (int r = 0; r < 5; ++r) {
            int oy = oy0 + 2 * r;
            sm[oc * 187 + (oy + 1) * 17 + (ox + 1)] = fmaxf(acc[r8][r] + bias, 0.f);
        }
    }
    __syncthreads();

    // phase C: conv3 (1 oc x 5 oy rows per thread), 16 chunks of 4 ic
    const int oc3 = t >> 3, ox3 = t & 7;
    float a3[5] = {0.f, 0.f, 0.f, 0.f, 0.f};
#pragma unroll 1
    for (int icc = 0; icc < 16; ++icc) {
        for (int l = t; l < 1152; l += 256) {
            int oc = l / 36;
            int j  = l - oc * 36;
            sm[O_W3C + l] = w3[oc * 576 + icc * 36 + j];
        }
        __syncthreads();
        const int ab = icc * 4 * 187;
#pragma unroll
        for (int ic = 0; ic < 4; ++ic) {
#pragma unroll
            for (int ky = 0; ky < 3; ++ky) {
#pragma unroll
                for (int kx = 0; kx < 3; ++kx) {
                    float w = sm[O_W3C + oc3 * 36 + ic * 9 + ky * 3 + kx];
#pragma unroll
                    for (int r = 0; r < 5; ++r)
                        a3[r] = fmaf(w, sm[ab + ic * 187 + (2 * r + ky) * 17 + (2 * ox3 + kx)], a3[r]);
                }
            }
        }
        __syncthreads();
    }
    float b3v = sm[O_B3S + oc3];
#pragma unroll
    for (int r = 0; r < 5; ++r)
        seq[(long)img * 1283 + oc3 * 40 + r * 8 + ox3] = fmaxf(a3[r] + b3v, 0.f);
    if (t < 3) seq[(long)img * 1283 + 1280 + t] = relpos[img * 3 + t];
}

// ---------------------------------------------------------------------------
// Sensory synapse sums for all 2048 (b,s) pairs, 4 pairs per block.
// ---------------------------------------------------------------------------
__global__ __launch_bounds__(256) void sensory_kernel(
    const float* __restrict__ sp, const float* __restrict__ seq,
    const float* __restrict__ iw, const float* __restrict__ ibias,
    float* __restrict__ wnum, float* __restrict__ wden) {
    const float* SW  = sp;
    const float* SWE = sp + SSTRIDE;
    const float* SA  = sp + 2 * SSTRIDE;
    const float* SB  = sp + 3 * SSTRIDE;
    __shared__ float I[4 * 1283];
    __shared__ float red[4][4][64][2];  // [kg][p][u][num/den] (u padded to 64)
    const int t  = threadIdx.x;
    const int pb = blockIdx.x * 4;

    for (int l = t; l < 4 * 1283; l += 256) {
        int p = l / 1283;
        int k = l - p * 1283;
        I[l] = fmaf(seq[(long)pb * 1283 + l], iw[k], ibias[k]);
    }
    __syncthreads();

    const int u = t & 63, kg = t >> 6;
    const bool uval = u < 48;
    float n0 = 0, n1 = 0, n2 = 0, n3 = 0, d0 = 0, d1 = 0, d2 = 0, d3 = 0;
    for (int k = kg; k < 1283; k += 4) {
        int idx = k * 48 + u;  // u>=48 reads pad region (discarded)
        float A = SA[idx], Bc = SB[idx], w = SW[idx], we = SWE[idx];
        float r0 = __builtin_amdgcn_rcpf(1.f + __builtin_amdgcn_exp2f(fmaf(A, I[k], Bc)));
        float r1 = __builtin_amdgcn_rcpf(1.f + __builtin_amdgcn_exp2f(fmaf(A, I[1283 + k], Bc)));
        float r2 = __builtin_amdgcn_rcpf(1.f + __builtin_amdgcn_exp2f(fmaf(A, I[2566 + k], Bc)));
        float r3 = __builtin_amdgcn_rcpf(1.f + __builtin_amdgcn_exp2f(fmaf(A, I[3849 + k], Bc)));
        n0 = fmaf(we, r0, n0); d0 = fmaf(w, r0, d0);
        n1 = fmaf(we, r1, n1); d1 = fmaf(w, r1, d1);
        n2 = fmaf(we, r2, n2); d2 = fmaf(w, r2, d2);
        n3 = fmaf(we, r3, n3); d3 = fmaf(w, r3, d3);
    }
    if (uval) {
        red[kg][0][u][0] = n0; red[kg][0][u][1] = d0;
        red[kg][1][u][0] = n1; red[kg][1][u][1] = d1;
        red[kg][2][u][0] = n2; red[kg][2][u][1] = d2;
        red[kg][3][u][0] = n3; red[kg][3][u][1] = d3;
    }
    __syncthreads();
    if (t < 192) {
        int p = t / 48, uu = t - p * 48;
        float n = red[0][p][uu][0] + red[1][p][uu][0] + red[2][p][uu][0] + red[3][p][uu][0];
        float d = red[0][p][uu][1] + red[1][p][uu][1] + red[2][p][uu][1] + red[3][p][uu][1];
        wnum[(long)(pb + p) * 48 + uu] = n;
        wden[(long)(pb + p) * 48 + uu] = d;
    }
}

// ---------------------------------------------------------------------------
// Recurrent LTC scan: one block per batch element (64 blocks x 256 threads).
// Threads: u = t&63 (48 valid units), jg = t>>6 (4 groups of 12 presyn j).
// ---------------------------------------------------------------------------
__global__ __launch_bounds__(256) void recurrent_kernel(
    const float* __restrict__ rp, const float* __restrict__ cmglv,
    const float* __restrict__ wnum, const float* __restrict__ wden,
    const float* __restrict__ out_w, const float* __restrict__ out_b,
    const float* __restrict__ head_w, const float* __restrict__ head_b,
    float* __restrict__ outp) {
    __shared__ float RW[RSTRIDE], RWE[RSTRIDE], RA[RSTRIDE], RB[RSTRIDE];
    __shared__ float v[48];
    __shared__ float red[4][64][2];
    __shared__ float ym[4];
    const int t = threadIdx.x, b = blockIdx.x;
    for (int l = t; l < 2304; l += 256) {
        RW[l]  = rp[l];
        RWE[l] = rp[RSTRIDE + l];
        RA[l]  = rp[2 * RSTRIDE + l];
        RB[l]  = rp[3 * RSTRIDE + l];
    }
    if (t < 48) v[t] = 0.f;
    const int u = t & 63, jg = t >> 6;
    const bool uval = u < 48;
    float cmt = 0.f, gl = 0.f, glv = 0.f;
    if (uval) { cmt = cmglv[u]; gl = cmglv[64 + u]; glv = cmglv[128 + u]; }
    __syncthreads();

    float yacc = 0.f;
    const int j0 = jg * 12;
    for (int s = 0; s < 32; ++s) {
        float wn = 0.f, wd = 0.f;
        if (uval) {
            wn = wnum[((long)b * 32 + s) * 48 + u];
            wd = wden[((long)b * 32 + s) * 48 + u];
        }
#pragma unroll 1
        for (int unf = 0; unf < 6; ++unf) {
            float vu = uval ? v[u] : 0.f;
            float pn = 0.f, pd = 0.f;
#pragma unroll
            for (int jj = 0; jj < 12; ++jj) {
                int j = j0 + jj;
                float vj = v[j];
                int idx = j * 48 + u;  // u>=48 reads LDS pad (discarded)
                float r = __builtin_amdgcn_rcpf(1.f + __builtin_amdgcn_exp2f(fmaf(RA[idx], vj, RB[idx])));
                pn = fmaf(RWE[idx], r, pn);
                pd = fmaf(RW[idx], r, pd);
            }
            if (uval) { red[jg][u][0] = pn; red[jg][u][1] = pd; }
            __syncthreads();
            float sn = red[0][u][0] + red[1][u][0] + red[2][u][0] + red[3][u][0];
            float sd = red[0][u][1] + red[1][u][1] + red[2][u][1] + red[3][u][1];
            float num = fmaf(cmt, vu, glv) + sn + wn;
            float den = cmt + gl + sd + wd;
            float vn = num / (den + 1e-8f);
            if (jg == 0 && uval) v[u] = vn;
            __syncthreads();
        }
        if (t < 4) yacc += v[t] * out_w[t] + out_b[t];
    }
    if (t < 4) ym[t] = yacc;
    __syncthreads();
    if (t < 2) {
        const float inv = 1.f / 32.f;
        float o = ym[0] * inv * head_w[t] + ym[1] * inv * head_w[2 + t] +
                  ym[2] * inv * head_w[4 + t] + ym[3] * inv * head_w[6 + t] + head_b[t];
        outp[b * 2 + t] = tanhf(o);
    }
}

extern "C" void kernel_launch(void* const* d_in, const int* in_sizes, int n_in,
                              void* d_out, int out_size, void* d_ws, size_t ws_size,
                              hipStream_t stream) {
    const float* depth      = (const float*)d_in[0];
    const float* relpos     = (const float*)d_in[1];
    const float* w1         = (const float*)d_in[2];
    const float* b1         = (const float*)d_in[3];
    const float* w2         = (const float*)d_in[4];
    const float* b2         = (const float*)d_in[5];
    const float* w3         = (const float*)d_in[6];
    const float* b3         = (const float*)d_in[7];
    const float* iw         = (const float*)d_in[8];
    const float* ibias      = (const float*)d_in[9];
    const float* sens_w     = (const float*)d_in[10];
    const float* sens_mu    = (const float*)d_in[11];
    const float* sens_sigma = (const float*)d_in[12];
    const float* sens_erev  = (const float*)d_in[13];
    const float* rec_w      = (const float*)d_in[14];
    const float* rec_mu     = (const float*)d_in[15];
    const float* rec_sigma  = (const float*)d_in[16];
    const float* rec_erev   = (const float*)d_in[17];
    const float* gleak      = (const float*)d_in[18];
    const float* vleak      = (const float*)d_in[19];
    const float* cm         = (const float*)d_in[20];
    const float* out_w      = (const float*)d_in[21];
    const float* out_b      = (const float*)d_in[22];
    const float* head_w     = (const float*)d_in[23];
    const float* head_b     = (const float*)d_in[24];
    const int*   sens_mask  = (const int*)d_in[25];
    const int*   rec_mask   = (const int*)d_in[26];

    float* ws   = (float*)d_ws;
    float* out  = (float*)d_out;
    float* seq  = ws + OFF_SEQ;
    float* spar = ws + OFF_SW;
    float* rpar = ws + OFF_RW;
    float* cmglv = ws + OFF_CM;
    float* wn   = ws + OFF_WN;
    float* wd   = ws + OFF_WD;

    prep_kernel<<<250, 256, 0, stream>>>(sens_w, sens_mu, sens_sigma, sens_erev, sens_mask,
                                         rec_w, rec_mu, rec_sigma, rec_erev, rec_mask,
                                         gleak, vleak, cm, ws);
    cnn_kernel<<<2048, 256, 0, stream>>>(depth, relpos, w1, b1, w2, b2, w3, b3, seq);
    sensory_kernel<<<512, 256, 0, stream>>>(spar, seq, iw, ibias, wn, wd);
    recurrent_kernel<<<64, 256, 0, stream>>>(rpar, cmglv, wn, wd, out_w, out_b, head_w, head_b, out);
}

// Round 2
// 945.329 us; speedup vs baseline: 2.6013x; 2.6013x over previous
//
#include <hip/hip_runtime.h>
#include <hip/hip_bf16.h>

// Shapes: B=64 S=32 H=40 W=64 ; conv1: 1->32 (20x32) ; conv2: 32->64 (10x16) ; conv3: 64->32 (5x8)
// SENS=1283 UNITS=48 MOTOR=4 NA=2 UNFOLDS=6

constexpr int NSENS = 1283 * 48;      // 61584
constexpr int NREC  = 48 * 48;        // 2304
constexpr int SSTRIDE = 61648;        // padded (+64) so lanes u in [48,64) read in-bounds
constexpr int RSTRIDE = 2368;

constexpr long OFF_SEQ = 0;                       // 2048*1283 = 2627584 floats
constexpr long OFF_SW  = 2627584;                 // 4 arrays x SSTRIDE
constexpr long OFF_RW  = OFF_SW + 4L * SSTRIDE;   // 4 arrays x RSTRIDE
constexpr long OFF_CM  = OFF_RW + 4L * RSTRIDE;   // cm_t(64), gl(64), glv(64)
constexpr long OFF_WN  = OFF_CM + 192;            // 2048*48 (ALSO hosts w2t/w3t between prep and cnn)
constexpr long OFF_WD  = OFF_WN + 98304;          // 2048*48
// w2t (18432 fl) + w3t (18432 fl) live at OFF_WN until cnn_kernel finishes;
// sensory_kernel then overwrites that region with wnum (stream-ordered, safe).

__device__ __forceinline__ float sp_(float x) {
    return fmaxf(x, 0.f) + log1pf(expf(-fabsf(x)));   // stable softplus
}

// ---------------------------------------------------------------------------
// prep: fold LTC params + transpose conv weights to [ky][kx][ic][oc].
// sigmoid(sigma*(x-mu)) = rcp(1 + exp2(A*x + Bc)); A=-sigma*log2e, Bc=sigma*mu*log2e
// ---------------------------------------------------------------------------
__global__ void prep_kernel(const float* __restrict__ sens_w, const float* __restrict__ sens_mu,
                            const float* __restrict__ sens_sigma, const float* __restrict__ sens_erev,
                            const int* __restrict__ sens_mask,
                            const float* __restrict__ rec_w, const float* __restrict__ rec_mu,
                            const float* __restrict__ rec_sigma, const float* __restrict__ rec_erev,
                            const int* __restrict__ rec_mask,
                            const float* __restrict__ gleak, const float* __restrict__ vleak,
                            const float* __restrict__ cm,
                            const float* __restrict__ w2, const float* __restrict__ w3,
                            float* __restrict__ ws) {
    const float L2E = 1.4426950408889634f;
    int i = blockIdx.x * 256 + threadIdx.x;
    if (i < NSENS) {
        float m  = sens_mask[i] ? 1.f : 0.f;
        float sw = sp_(sens_w[i]) * m;
        float sg = sens_sigma[i], mu = sens_mu[i];
        ws[OFF_SW + i]               = sw;
        ws[OFF_SW + SSTRIDE + i]     = sw * sens_erev[i];
        ws[OFF_SW + 2 * SSTRIDE + i] = -sg * L2E;
        ws[OFF_SW + 3 * SSTRIDE + i] = sg * mu * L2E;
    } else if (i < NSENS + NREC) {
        int j = i - NSENS;
        float m  = rec_mask[j] ? 1.f : 0.f;
        float sw = sp_(rec_w[j]) * m;
        float sg = rec_sigma[j], mu = rec_mu[j];
        ws[OFF_RW + j]               = sw;
        ws[OFF_RW + RSTRIDE + j]     = sw * rec_erev[j];
        ws[OFF_RW + 2 * RSTRIDE + j] = -sg * L2E;
        ws[OFF_RW + 3 * RSTRIDE + j] = sg * mu * L2E;
    } else if (i < NSENS + NREC + 48) {
        int u = i - (NSENS + NREC);
        float g = sp_(gleak[u]);
        ws[OFF_CM + u]        = sp_(cm[u]) * 6.f;
        ws[OFF_CM + 64 + u]   = g;
        ws[OFF_CM + 128 + u]  = g * vleak[u];
    } else if (i < NSENS + NREC + 48 + 18432) {
        int j = i - (NSENS + NREC + 48);          // w2t[(ky*3+kx)*32+ic][oc]
        int pos = j >> 11, ic = (j >> 6) & 31, oc = j & 63;
        int ky = pos / 3, kx = pos % 3;
        ws[OFF_WN + j] = w2[((oc * 32 + ic) * 3 + ky) * 3 + kx];
    } else if (i < NSENS + NREC + 48 + 36864) {
        int j = i - (NSENS + NREC + 48 + 18432);  // w3t[(ky*3+kx)*64+ic][oc]
        int pos = j >> 11, rest = j & 2047;
        int ic = rest >> 5, oc = rest & 31;
        int ky = pos / 3, kx = pos % 3;
        ws[OFF_WN + 18432 + j] = w3[((oc * 64 + ic) * 3 + ky) * 3 + kx];
    }
}

// ---------------------------------------------------------------------------
// Fused CNN: one block per image, NHWC 4-ch groups, even/odd x-column split so
// every stride-2 read is a contiguous float4 (ds_read_b128). 52 KB LDS -> 3 blk/CU.
// Phase A/B (per 8-ch chunk): conv1 -> c1 in LDS; conv2 accumulates in regs.
// Phase C: acc -> a2 in LDS; conv3 with 4-way ic-split + LDS reduction.
// ---------------------------------------------------------------------------
#define O_IMG 0        // [41][65] rows y=-1..39, cols x=-1..63 (zero pad)
#define O_C1E 2668     // [2][21][16][4]  g*1344 + row*64 + ex*4   (even x1)
#define O_C1O 5356     // [2][21][17][4]  g*1428 + row*68 + ox*4   (odd x1, col0 = x1=-1 pad)
#define O_W2S 8212     // [3 kx][8 ic][64 oc]
#define O_W1  9748     // [32][9]
#define O_B1  10036
#define O_B2  10068    // 64
// phase C (overlaps dead phase-A regions):
#define O_A2E 0        // [16][11][8][4]  g*352 + row*32 + ex*4
#define O_A2O 5632     // [16][11][9][4]  g*396 + row*36 + ox*4   (col0 = x2=-1 pad)
#define O_W3S 11968    // [32 ic][32 oc] half-ic chunk
#define O_PART 0       // [256][20] partials (written after all a2 reads done)
#define O_B3  12992
#define SM_TOTAL 13024 // floats = 52,096 B -> 3 blocks/CU

__global__ __launch_bounds__(256) void cnn_kernel(
    const float* __restrict__ depth, const float* __restrict__ relpos,
    const float* __restrict__ w1, const float* __restrict__ b1,
    const float* __restrict__ b2, const float* __restrict__ b3,
    const float* __restrict__ w2t, const float* __restrict__ w3t,
    float* __restrict__ seq) {
    __shared__ float sm[SM_TOTAL];
    const int t = threadIdx.x;
    const int img = blockIdx.x;

    // init: zero img pads + c1 (pads persist; conv1 rewrites interior each chunk)
    for (int l = t; l < 2665; l += 256) sm[O_IMG + l] = 0.f;
    for (int l = t; l < 5544; l += 256) sm[O_C1E + l] = 0.f;  // c1e+c1o contiguous
    for (int l = t; l < 288; l += 256) sm[O_W1 + l] = w1[l];
    if (t < 32) sm[O_B1 + t] = b1[t];
    if (t < 64) sm[O_B2 + t] = b2[t];
    if (t < 32) sm[O_B3 + t] = b3[t];
    __syncthreads();
    for (int l = t; l < 2560; l += 256) {
        int h = l >> 6, w = l & 63;
        sm[O_IMG + (h + 1) * 65 + (w + 1)] = depth[(long)img * 2560 + l];
    }
    __syncthreads();

    // conv2 thread mapping: ocg = t>>5 (8 oc), pxg = t&31 ; px r -> flat = pxg+32r
    const int ocg = t >> 5, pxg = t & 31;
    float acc[2][4][5];
#pragma unroll
    for (int q = 0; q < 2; ++q)
#pragma unroll
        for (int j = 0; j < 4; ++j) {
            float bb = sm[O_B2 + ocg * 8 + q * 4 + j];
#pragma unroll
            for (int r = 0; r < 5; ++r) acc[q][j][r] = bb;
        }

#pragma unroll 1
    for (int cc = 0; cc < 4; ++cc) {   // 4 chunks of 8 conv1 channels
        // ---- conv1: 8 channels of this chunk into c1e/c1o ----
        float iv[3][9];
#pragma unroll
        for (int pp = 0; pp < 3; ++pp) {
            int p = t + (pp << 8);
            if (p < 640) {
                int y1 = p >> 5, x1 = p & 31;
#pragma unroll
                for (int ky = 0; ky < 3; ++ky)
#pragma unroll
                    for (int kx = 0; kx < 3; ++kx)
                        iv[pp][ky * 3 + kx] = sm[O_IMG + (2 * y1 + ky) * 65 + (2 * x1 + kx)];
            }
        }
#pragma unroll 1
        for (int j = 0; j < 8; ++j) {
            int oc = cc * 8 + j;
            float wv[9];
#pragma unroll
            for (int k = 0; k < 9; ++k) wv[k] = sm[O_W1 + oc * 9 + k];
            float bb = sm[O_B1 + oc];
            int g = j >> 2, sub = j & 3;
#pragma unroll
            for (int pp = 0; pp < 3; ++pp) {
                int p = t + (pp << 8);
                if (p < 640) {
                    float a = bb;
#pragma unroll
                    for (int k = 0; k < 9; ++k) a = fmaf(wv[k], iv[pp][k], a);
                    a = fmaxf(a, 0.f);
                    int y1 = p >> 5, x1 = p & 31, row = y1 + 1;
                    if (x1 & 1) sm[O_C1O + g * 1428 + row * 68 + ((x1 + 1) >> 1) * 4 + sub] = a;
                    else        sm[O_C1E + g * 1344 + row * 64 + (x1 >> 1) * 4 + sub] = a;
                }
            }
        }
        __syncthreads();

        // ---- conv2 accumulate over this chunk's 8 ic ----
#pragma unroll 1
        for (int ky = 0; ky < 3; ++ky) {
            for (int l = t; l < 1536; l += 256) {   // stage w2 [3kx][8ic][64oc], coalesced
                int kx = l >> 9, ic = (l >> 6) & 7, oc = l & 63;
                sm[O_W2S + l] = w2t[((ky * 3 + kx) * 32 + cc * 8 + ic) * 64 + oc];
            }
            __syncthreads();
#pragma unroll
            for (int kx = 0; kx < 3; ++kx) {
#pragma unroll
                for (int g = 0; g < 2; ++g) {
                    float xv[5][4];
#pragma unroll
                    for (int r = 0; r < 5; ++r) {
                        int flat = pxg + (r << 5);
                        int y2 = flat >> 4, x2 = flat & 15;
                        int row = 2 * y2 + ky;
                        int idx;
                        if (kx == 1)      idx = O_C1E + g * 1344 + row * 64 + x2 * 4;
                        else if (kx == 0) idx = O_C1O + g * 1428 + row * 68 + x2 * 4;
                        else              idx = O_C1O + g * 1428 + row * 68 + (x2 + 1) * 4;
                        *(float4*)&xv[r][0] = *(const float4*)&sm[idx];
                    }
#pragma unroll
                    for (int q = 0; q < 2; ++q)
#pragma unroll
                        for (int i = 0; i < 4; ++i) {
                            float4 wv = *(const float4*)&sm[O_W2S + kx * 512 + (g * 4 + i) * 64 + ocg * 8 + q * 4];
#pragma unroll
                            for (int r = 0; r < 5; ++r) {
                                float x = xv[r][i];
                                acc[q][0][r] = fmaf(wv.x, x, acc[q][0][r]);
                                acc[q][1][r] = fmaf(wv.y, x, acc[q][1][r]);
                                acc[q][2][r] = fmaf(wv.z, x, acc[q][2][r]);
                                acc[q][3][r] = fmaf(wv.w, x, acc[q][3][r]);
                            }
                        }
                }
            }
            __syncthreads();
        }
    }

    // ---- phase C: acc -> a2 (relu), zero pads first ----
    for (int l = t; l < 512; l += 256) { int g = l >> 5, x = l & 31; sm[O_A2E + g * 352 + x] = 0.f; }
    for (int l = t; l < 576; l += 256) { int g = l / 36, rest = l - g * 36; sm[O_A2O + g * 396 + rest] = 0.f; }
    for (int l = t; l < 704; l += 256) { int g = l / 44, rest = l - g * 44; sm[O_A2O + g * 396 + (rest >> 2) * 36 + (rest & 3)] = 0.f; }
    __syncthreads();
#pragma unroll
    for (int q = 0; q < 2; ++q) {
        int g2 = ocg * 2 + q;
#pragma unroll
        for (int r = 0; r < 5; ++r) {
            int flat = pxg + (r << 5);
            int y2 = flat >> 4, x2 = flat & 15, row = y2 + 1;
            float4 v = make_float4(fmaxf(acc[q][0][r], 0.f), fmaxf(acc[q][1][r], 0.f),
                                   fmaxf(acc[q][2][r], 0.f), fmaxf(acc[q][3][r], 0.f));
            int idx = (x2 & 1) ? (O_A2O + g2 * 396 + row * 36 + ((x2 + 1) >> 1) * 4)
                               : (O_A2E + g2 * 352 + row * 32 + (x2 >> 1) * 4);
            *(float4*)&sm[idx] = v;
        }
    }
    __syncthreads();

    // ---- conv3: thread = (icslice 4) x (ocq 8: 4 oc) x (x3 8); all 5 y3 ----
    const int icslice = t >> 6, ocq = (t >> 3) & 7, x3 = t & 7;
    float a3[4][5];
#pragma unroll
    for (int j = 0; j < 4; ++j)
#pragma unroll
        for (int r = 0; r < 5; ++r) a3[j][r] = 0.f;

#pragma unroll 1
    for (int ky = 0; ky < 3; ++ky) {
#pragma unroll 1
        for (int kx = 0; kx < 3; ++kx) {
            int pos = ky * 3 + kx;
#pragma unroll 1
            for (int ih = 0; ih < 2; ++ih) {
                for (int l = t; l < 1024; l += 256)   // stage w3 [32ic][32oc], coalesced
                    sm[O_W3S + l] = w3t[(pos * 64 + ih * 32 + (l >> 5)) * 32 + (l & 31)];
                __syncthreads();
#pragma unroll
                for (int gg = 0; gg < 2; ++gg) {
                    int gl = icslice * 2 + gg;       // ic-quad within staged half
                    int g = ih * 8 + gl;             // a2 channel group
                    float xv[5][4];
#pragma unroll
                    for (int r = 0; r < 5; ++r) {
                        int row = 2 * r + ky;
                        int idx;
                        if (kx == 1)      idx = O_A2E + g * 352 + row * 32 + x3 * 4;
                        else if (kx == 0) idx = O_A2O + g * 396 + row * 36 + x3 * 4;
                        else              idx = O_A2O + g * 396 + row * 36 + (x3 + 1) * 4;
                        *(float4*)&xv[r][0] = *(const float4*)&sm[idx];
                    }
#pragma unroll
                    for (int i = 0; i < 4; ++i) {
                        float4 wv = *(const float4*)&sm[O_W3S + (gl * 4 + i) * 32 + ocq * 4];
#pragma unroll
                        for (int r = 0; r < 5; ++r) {
                            float x = xv[r][i];
                            a3[0][r] = fmaf(wv.x, x, a3[0][r]);
                            a3[1][r] = fmaf(wv.y, x, a3[1][r]);
                            a3[2][r] = fmaf(wv.z, x, a3[2][r]);
                            a3[3][r] = fmaf(wv.w, x, a3[3][r]);
                        }
                    }
                }
                __syncthreads();
            }
        }
    }

    // partial reduction over the 4 ic-slices
#pragma unroll
    for (int r = 0; r < 5; ++r)
        *(float4*)&sm[O_PART + t * 20 + r * 4] = make_float4(a3[0][r], a3[1][r], a3[2][r], a3[3][r]);
    __syncthreads();
#pragma unroll
    for (int k = 0; k < 5; ++k) {
        int o = t * 5 + k;
        int oc = o / 40, rem = o - oc * 40;
        int y3 = rem >> 3, xx = rem & 7;
        float v = sm[O_B3 + oc];
        int base = (oc >> 2) * 8 + xx, elem = y3 * 4 + (oc & 3);
#pragma unroll
        for (int s = 0; s < 4; ++s) v += sm[O_PART + (s * 64 + base) * 20 + elem];
        seq[(long)img * 1283 + oc * 40 + y3 * 8 + xx] = fmaxf(v, 0.f);
    }
    if (t < 3) seq[(long)img * 1283 + 1280 + t] = relpos[img * 3 + t];
}

// ---------------------------------------------------------------------------
// Sensory synapse sums for all 2048 (b,s) pairs, 4 pairs per block.
// ---------------------------------------------------------------------------
__global__ __launch_bounds__(256) void sensory_kernel(
    const float* __restrict__ sp, const float* __restrict__ seq,
    const float* __restrict__ iw, const float* __restrict__ ibias,
    float* __restrict__ wnum, float* __restrict__ wden) {
    const float* SW  = sp;
    const float* SWE = sp + SSTRIDE;
    const float* SA  = sp + 2 * SSTRIDE;
    const float* SB  = sp + 3 * SSTRIDE;
    __shared__ float I[4 * 1283];
    __shared__ float red[4][4][64][2];
    const int t  = threadIdx.x;
    const int pb = blockIdx.x * 4;

    for (int l = t; l < 4 * 1283; l += 256) {
        int p = l / 1283;
        int k = l - p * 1283;
        I[l] = fmaf(seq[(long)pb * 1283 + l], iw[k], ibias[k]);
    }
    __syncthreads();

    const int u = t & 63, kg = t >> 6;
    const bool uval = u < 48;
    float n0 = 0, n1 = 0, n2 = 0, n3 = 0, d0 = 0, d1 = 0, d2 = 0, d3 = 0;
    for (int k = kg; k < 1283; k += 4) {
        int idx = k * 48 + u;
        float A = SA[idx], Bc = SB[idx], w = SW[idx], we = SWE[idx];
        float r0 = __builtin_amdgcn_rcpf(1.f + __builtin_amdgcn_exp2f(fmaf(A, I[k], Bc)));
        float r1 = __builtin_amdgcn_rcpf(1.f + __builtin_amdgcn_exp2f(fmaf(A, I[1283 + k], Bc)));
        float r2 = __builtin_amdgcn_rcpf(1.f + __builtin_amdgcn_exp2f(fmaf(A, I[2566 + k], Bc)));
        float r3 = __builtin_amdgcn_rcpf(1.f + __builtin_amdgcn_exp2f(fmaf(A, I[3849 + k], Bc)));
        n0 = fmaf(we, r0, n0); d0 = fmaf(w, r0, d0);
        n1 = fmaf(we, r1, n1); d1 = fmaf(w, r1, d1);
        n2 = fmaf(we, r2, n2); d2 = fmaf(w, r2, d2);
        n3 = fmaf(we, r3, n3); d3 = fmaf(w, r3, d3);
    }
    if (uval) {
        red[kg][0][u][0] = n0; red[kg][0][u][1] = d0;
        red[kg][1][u][0] = n1; red[kg][1][u][1] = d1;
        red[kg][2][u][0] = n2; red[kg][2][u][1] = d2;
        red[kg][3][u][0] = n3; red[kg][3][u][1] = d3;
    }
    __syncthreads();
    if (t < 192) {
        int p = t / 48, uu = t - p * 48;
        float n = red[0][p][uu][0] + red[1][p][uu][0] + red[2][p][uu][0] + red[3][p][uu][0];
        float d = red[0][p][uu][1] + red[1][p][uu][1] + red[2][p][uu][1] + red[3][p][uu][1];
        wnum[(long)(pb + p) * 48 + uu] = n;
        wden[(long)(pb + p) * 48 + uu] = d;
    }
}

// ---------------------------------------------------------------------------
// Recurrent LTC scan: one block per batch element.
// ---------------------------------------------------------------------------
__global__ __launch_bounds__(256) void recurrent_kernel(
    const float* __restrict__ rp, const float* __restrict__ cmglv,
    const float* __restrict__ wnum, const float* __restrict__ wden,
    const float* __restrict__ out_w, const float* __restrict__ out_b,
    const float* __restrict__ head_w, const float* __restrict__ head_b,
    float* __restrict__ outp) {
    __shared__ float RW[RSTRIDE], RWE[RSTRIDE], RA[RSTRIDE], RB[RSTRIDE];
    __shared__ float v[48];
    __shared__ float red[4][64][2];
    __shared__ float ym[4];
    const int t = threadIdx.x, b = blockIdx.x;
    for (int l = t; l < 2304; l += 256) {
        RW[l]  = rp[l];
        RWE[l] = rp[RSTRIDE + l];
        RA[l]  = rp[2 * RSTRIDE + l];
        RB[l]  = rp[3 * RSTRIDE + l];
    }
    if (t < 48) v[t] = 0.f;
    const int u = t & 63, jg = t >> 6;
    const bool uval = u < 48;
    float cmt = 0.f, gl = 0.f, glv = 0.f;
    if (uval) { cmt = cmglv[u]; gl = cmglv[64 + u]; glv = cmglv[128 + u]; }
    __syncthreads();

    float yacc = 0.f;
    const int j0 = jg * 12;
    for (int s = 0; s < 32; ++s) {
        float wn = 0.f, wd = 0.f;
        if (uval) {
            wn = wnum[((long)b * 32 + s) * 48 + u];
            wd = wden[((long)b * 32 + s) * 48 + u];
        }
#pragma unroll 1
        for (int unf = 0; unf < 6; ++unf) {
            float vu = uval ? v[u] : 0.f;
            float pn = 0.f, pd = 0.f;
#pragma unroll
            for (int jj = 0; jj < 12; ++jj) {
                int j = j0 + jj;
                float vj = v[j];
                int idx = j * 48 + u;
                float r = __builtin_amdgcn_rcpf(1.f + __builtin_amdgcn_exp2f(fmaf(RA[idx], vj, RB[idx])));
                pn = fmaf(RWE[idx], r, pn);
                pd = fmaf(RW[idx], r, pd);
            }
            if (uval) { red[jg][u][0] = pn; red[jg][u][1] = pd; }
            __syncthreads();
            float sn = red[0][u][0] + red[1][u][0] + red[2][u][0] + red[3][u][0];
            float sd = red[0][u][1] + red[1][u][1] + red[2][u][1] + red[3][u][1];
            float num = fmaf(cmt, vu, glv) + sn + wn;
            float den = cmt + gl + sd + wd;
            float vn = num / (den + 1e-8f);
            if (jg == 0 && uval) v[u] = vn;
            __syncthreads();
        }
        if (t < 4) yacc += v[t] * out_w[t] + out_b[t];
    }
    if (t < 4) ym[t] = yacc;
    __syncthreads();
    if (t < 2) {
        const float inv = 1.f / 32.f;
        float o = ym[0] * inv * head_w[t] + ym[1] * inv * head_w[2 + t] +
                  ym[2] * inv * head_w[4 + t] + ym[3] * inv * head_w[6 + t] + head_b[t];
        outp[b * 2 + t] = tanhf(o);
    }
}

extern "C" void kernel_launch(void* const* d_in, const int* in_sizes, int n_in,
                              void* d_out, int out_size, void* d_ws, size_t ws_size,
                              hipStream_t stream) {
    const float* depth      = (const float*)d_in[0];
    const float* relpos     = (const float*)d_in[1];
    const float* w1         = (const float*)d_in[2];
    const float* b1         = (const float*)d_in[3];
    const float* w2         = (const float*)d_in[4];
    const float* b2         = (const float*)d_in[5];
    const float* w3         = (const float*)d_in[6];
    const float* b3         = (const float*)d_in[7];
    const float* iw         = (const float*)d_in[8];
    const float* ibias      = (const float*)d_in[9];
    const float* sens_w     = (const float*)d_in[10];
    const float* sens_mu    = (const float*)d_in[11];
    const float* sens_sigma = (const float*)d_in[12];
    const float* sens_erev  = (const float*)d_in[13];
    const float* rec_w      = (const float*)d_in[14];
    const float* rec_mu     = (const float*)d_in[15];
    const float* rec_sigma  = (const float*)d_in[16];
    const float* rec_erev   = (const float*)d_in[17];
    const float* gleak      = (const float*)d_in[18];
    const float* vleak      = (const float*)d_in[19];
    const float* cm         = (const float*)d_in[20];
    const float* out_w      = (const float*)d_in[21];
    const float* out_b      = (const float*)d_in[22];
    const float* head_w     = (const float*)d_in[23];
    const float* head_b     = (const float*)d_in[24];
    const int*   sens_mask  = (const int*)d_in[25];
    const int*   rec_mask   = (const int*)d_in[26];

    float* ws    = (float*)d_ws;
    float* out   = (float*)d_out;
    float* seq   = ws + OFF_SEQ;
    float* spar  = ws + OFF_SW;
    float* rpar  = ws + OFF_RW;
    float* cmglv = ws + OFF_CM;
    float* wn    = ws + OFF_WN;
    float* wd    = ws + OFF_WD;
    float* w2t   = ws + OFF_WN;          // transient: consumed by cnn before sensory writes wn
    float* w3t   = ws + OFF_WN + 18432;

    prep_kernel<<<394, 256, 0, stream>>>(sens_w, sens_mu, sens_sigma, sens_erev, sens_mask,
                                         rec_w, rec_mu, rec_sigma, rec_erev, rec_mask,
                                         gleak, vleak, cm, w2, w3, ws);
    cnn_kernel<<<2048, 256, 0, stream>>>(depth, relpos, w1, b1, b2, b3, w2t, w3t, seq);
    sensory_kernel<<<512, 256, 0, stream>>>(spar, seq, iw, ibias, wn, wd);
    recurrent_kernel<<<64, 256, 0, stream>>>(rpar, cmglv, wn, wd, out_w, out_b, head_w, head_b, out);
}

// Round 3
// 776.911 us; speedup vs baseline: 3.1652x; 1.2168x over previous
//
#include <hip/hip_runtime.h>
#include <hip/hip_bf16.h>

// Shapes: B=64 S=32 H=40 W=64 ; conv1: 1->32 (20x32) ; conv2: 32->64 (10x16) ; conv3: 64->32 (5x8)
// SENS=1283 UNITS=48 MOTOR=4 NA=2 UNFOLDS=6

// ---- workspace layout (floats) ----
constexpr long OFF_SEQ = 0;                 // 2048*1283 = 2627584
constexpr long OFF_SP4 = 2627584;           // sensory params float4[1283*64] = 328448 fl
constexpr long OFF_RP4 = 2956032;           // rec params float4[48*64] = 12288 fl
constexpr long OFF_CM  = 2968320;           // cm_t(64), gl(64), gl*vleak(64)
constexpr long OFF_W2U = 2968512;           // conv2 weights [cc2][g2][ky][kx][oc64][ic4] = 18432 fl
constexpr long OFF_W3U = 2986944;           // conv3 weights [kykx9][oc32][icg16][ic4] = 18432 fl
constexpr long OFF_WN  = 3005376;           // 2048*48
constexpr long OFF_WD  = 3103680;           // 2048*48  (end 3201984 fl = 12.8 MB)

__device__ __forceinline__ float sp_(float x) {
    return fmaxf(x, 0.f) + log1pf(expf(-fabsf(x)));   // stable softplus
}

// ---------------------------------------------------------------------------
// prep: fold LTC params into float4 {A,B,WE,W} (sigmoid(sig*(x-mu)) =
// rcp(1+exp2(A*x+B))), and transpose conv2/conv3 weights for uniform loads.
// ---------------------------------------------------------------------------
__global__ void prep_kernel(const float* __restrict__ sens_w, const float* __restrict__ sens_mu,
                            const float* __restrict__ sens_sigma, const float* __restrict__ sens_erev,
                            const int* __restrict__ sens_mask,
                            const float* __restrict__ rec_w, const float* __restrict__ rec_mu,
                            const float* __restrict__ rec_sigma, const float* __restrict__ rec_erev,
                            const int* __restrict__ rec_mask,
                            const float* __restrict__ gleak, const float* __restrict__ vleak,
                            const float* __restrict__ cm,
                            const float* __restrict__ w2, const float* __restrict__ w3,
                            float* __restrict__ ws) {
    const float L2E = 1.4426950408889634f;
    int i = blockIdx.x * 256 + threadIdx.x;
    if (i < 82112) {                       // sensory: [k 1283][u 64]
        int k = i >> 6, u = i & 63;
        float4 v = make_float4(0.f, 0.f, 0.f, 0.f);
        if (u < 48) {
            int idx = k * 48 + u;
            float m  = sens_mask[idx] ? 1.f : 0.f;
            float sw = sp_(sens_w[idx]) * m;
            float sg = sens_sigma[idx], mu = sens_mu[idx];
            v = make_float4(-sg * L2E, sg * mu * L2E, sw * sens_erev[idx], sw);
        }
        ((float4*)(ws + OFF_SP4))[i] = v;
    } else if (i < 85184) {                // recurrent: [j 48][u 64]
        int q = i - 82112;
        int j = q >> 6, u = q & 63;
        float4 v = make_float4(0.f, 0.f, 0.f, 0.f);
        if (u < 48) {
            int idx = j * 48 + u;
            float m  = rec_mask[idx] ? 1.f : 0.f;
            float sw = sp_(rec_w[idx]) * m;
            float sg = rec_sigma[idx], mu = rec_mu[idx];
            v = make_float4(-sg * L2E, sg * mu * L2E, sw * rec_erev[idx], sw);
        }
        ((float4*)(ws + OFF_RP4))[q] = v;
    } else if (i < 85232) {
        int u = i - 85184;                 // u < 48
        float g = sp_(gleak[u]);
        ws[OFF_CM + u]       = sp_(cm[u]) * 6.f;
        ws[OFF_CM + 64 + u]  = g;
        ws[OFF_CM + 128 + u] = g * vleak[u];
    } else if (i < 103664) {               // w2u
        int n = i - 85232;
        int icw = n & 3, oc = (n >> 2) & 63, rest = n >> 8;
        int p = rest % 9, cg = rest / 9;   // cg = cc*2+g
        int cc = cg >> 1, g = cg & 1;
        int ky = p / 3, kx = p % 3;
        int ic = cc * 8 + g * 4 + icw;
        ws[OFF_W2U + n] = w2[((oc * 32 + ic) * 3 + ky) * 3 + kx];
    } else if (i < 122096) {               // w3u
        int n = i - 103664;
        int icw = n & 3, icg = (n >> 2) & 15, oc = (n >> 6) & 31, p = n >> 11;
        int ky = p / 3, kx = p % 3;
        int ic = icg * 4 + icw;
        ws[OFF_W3U + n] = w3[((oc * 64 + ic) * 3 + ky) * 3 + kx];
    }
}

// ---------------------------------------------------------------------------
// Fused CNN, one block per image. Activations in LDS (b128), weights via
// wave-uniform loads (SGPR operand in the FMA). 11 barriers total.
// LDS (floats): phase A: img[41][65]=2665 @0 | c1e[2][21][16][4]=2688 @2668 |
//               c1o[2][21][17][4]=2856 @5356  (end 8212)
//               phase C overlay: a2[11 rows][17 cols][68 ch-pad] = 12716 @0
// ---------------------------------------------------------------------------
#define O_IMG 0
#define O_C1E 2668
#define O_C1O 5356
#define SM_TOTAL 12716   // 50,864 B -> 3 blocks/CU

__global__ __launch_bounds__(256) void cnn_kernel(
    const float* __restrict__ depth, const float* __restrict__ relpos,
    const float* __restrict__ w1, const float* __restrict__ b1,
    const float* __restrict__ b2, const float* __restrict__ b3,
    const float* __restrict__ w2u, const float* __restrict__ w3u,
    float* __restrict__ seq) {
    __shared__ float sm[SM_TOTAL];
    const int t = threadIdx.x;
    const int img = blockIdx.x;
    const int wv_ = __builtin_amdgcn_readfirstlane(t >> 6);  // wave id 0..3 (uniform)
    const int l = t & 63;

    // zero img (incl pads) + c1 (incl pads)
    for (int i = t; i < 8212; i += 256) sm[i] = 0.f;
    __syncthreads();
    for (int i = t; i < 2560; i += 256) {
        int h = i >> 6, w = i & 63;
        sm[O_IMG + (h + 1) * 65 + (w + 1)] = depth[(long)img * 2560 + i];
    }
    __syncthreads();

    // conv2 lane px assignment: p0=l, p1=l+64, p2=l+128 (lanes<32 only)
    const int p0 = l, p1 = l + 64, p2 = (l < 32) ? l + 128 : l;
    const int py2[3] = {p0 >> 4, p1 >> 4, p2 >> 4};
    const int px2[3] = {p0 & 15, p1 & 15, p2 & 15};

    float acc[16][3];
#pragma unroll
    for (int q = 0; q < 16; ++q) {
        float bb = b2[wv_ * 16 + q];       // uniform
#pragma unroll
        for (int r = 0; r < 3; ++r) acc[q][r] = bb;
    }

    const float4* w2q4 = (const float4*)w2u;

#pragma unroll 1
    for (int cc = 0; cc < 4; ++cc) {
        // ---- conv1: 8 channels (cc*8..cc*8+7) -> c1e/c1o ----
#pragma unroll 1
        for (int pp = 0; pp < 3; ++pp) {
            int p = t + (pp << 8);
            if (p < 640) {
                int y1 = p >> 5, x1 = p & 31;
                float iv[9];
#pragma unroll
                for (int ky = 0; ky < 3; ++ky)
#pragma unroll
                    for (int kx = 0; kx < 3; ++kx)
                        iv[ky * 3 + kx] = sm[O_IMG + (2 * y1 + ky) * 65 + (2 * x1 + kx)];
                int row = y1 + 1;
                int so = (x1 & 1) ? (O_C1O + row * 68 + ((x1 + 1) >> 1) * 4)
                                  : (O_C1E + row * 64 + (x1 >> 1) * 4);
                int sstep = (x1 & 1) ? 1428 : 1344;
#pragma unroll
                for (int j = 0; j < 8; ++j) {
                    int oc = cc * 8 + j;
                    float a = b1[oc];                                  // uniform
#pragma unroll
                    for (int k = 0; k < 9; ++k) a = fmaf(w1[oc * 9 + k], iv[k], a);  // uniform w
                    sm[so + (j >> 2) * sstep + (j & 3)] = fmaxf(a, 0.f);
                }
            }
        }
        __syncthreads();

        // ---- conv2: wave's 16 oc x lane's 3 px, 8 ic of this chunk ----
#pragma unroll 1
        for (int ky = 0; ky < 3; ++ky) {
#pragma unroll
            for (int g = 0; g < 2; ++g) {
                float4 x[3][3];  // [kx][px]
#pragma unroll
                for (int i = 0; i < 3; ++i) {
                    int rr = 2 * py2[i] + ky;
                    int be = O_C1E + g * 1344 + rr * 64 + px2[i] * 4;
                    int bo = O_C1O + g * 1428 + rr * 68 + px2[i] * 4;
                    x[0][i] = *(const float4*)&sm[bo];
                    x[1][i] = *(const float4*)&sm[be];
                    x[2][i] = *(const float4*)&sm[bo + 4];
                }
                const float4* wq = w2q4 + ((cc * 2 + g) * 9 + ky * 3) * 64 + wv_ * 16;
#pragma unroll
                for (int q = 0; q < 16; ++q) {
                    float4 W0 = wq[q], W1 = wq[64 + q], W2 = wq[128 + q];
#pragma unroll
                    for (int i = 0; i < 3; ++i) {
                        float a = acc[q][i];
                        a = fmaf(W0.x, x[0][i].x, a); a = fmaf(W0.y, x[0][i].y, a);
                        a = fmaf(W0.z, x[0][i].z, a); a = fmaf(W0.w, x[0][i].w, a);
                        a = fmaf(W1.x, x[1][i].x, a); a = fmaf(W1.y, x[1][i].y, a);
                        a = fmaf(W1.z, x[1][i].z, a); a = fmaf(W1.w, x[1][i].w, a);
                        a = fmaf(W2.x, x[2][i].x, a); a = fmaf(W2.y, x[2][i].y, a);
                        a = fmaf(W2.z, x[2][i].z, a); a = fmaf(W2.w, x[2][i].w, a);
                        acc[q][i] = a;
                    }
                }
            }
        }
        __syncthreads();   // protect c1 before next conv1 overwrite / a2 overlay
    }

    // ---- phase C: write a2 (relu), zero pads; overlay on img/c1 ----
    for (int i = t; i < 1156; i += 256) sm[i] = 0.f;                    // row 0
    for (int i = t; i < 680; i += 256) {                                 // col 0, rows 1..10
        int r = i / 68;
        sm[(r + 1) * 1156 + (i - r * 68)] = 0.f;
    }
#pragma unroll
    for (int i = 0; i < 3; ++i) {
        if (i < 2 || l < 32) {
            int base = ((py2[i] + 1) * 17 + (px2[i] + 1)) * 68 + wv_ * 16;
#pragma unroll
            for (int q4 = 0; q4 < 4; ++q4) {
                *(float4*)&sm[base + q4 * 4] = make_float4(
                    fmaxf(acc[q4 * 4 + 0][i], 0.f), fmaxf(acc[q4 * 4 + 1][i], 0.f),
                    fmaxf(acc[q4 * 4 + 2][i], 0.f), fmaxf(acc[q4 * 4 + 3][i], 0.f));
            }
        }
    }
    __syncthreads();

    // ---- conv3: wave's 8 oc, lane = px (40 of 64 active), all 64 ic ----
    const bool a3act = l < 40;
    const int y3 = l >> 3, x3 = l & 7;
    float a3[8] = {0.f, 0.f, 0.f, 0.f, 0.f, 0.f, 0.f, 0.f};
    const float4* w3q4 = (const float4*)w3u;
#pragma unroll 1
    for (int ky = 0; ky < 3; ++ky) {
#pragma unroll 1
        for (int kx = 0; kx < 3; ++kx) {
            int rb = a3act ? ((2 * y3 + ky) * 17 + (2 * x3 + kx)) * 68 : 0;
            const float4* wp = w3q4 + ((ky * 3 + kx) * 32 + wv_ * 8) * 16;
#pragma unroll
            for (int icg = 0; icg < 16; ++icg) {
                float4 xv = *(const float4*)&sm[rb + icg * 4];
#pragma unroll
                for (int j = 0; j < 8; ++j) {
                    float4 W = wp[j * 16 + icg];
                    float a = a3[j];
                    a = fmaf(W.x, xv.x, a); a = fmaf(W.y, xv.y, a);
                    a = fmaf(W.z, xv.z, a); a = fmaf(W.w, xv.w, a);
                    a3[j] = a;
                }
            }
        }
    }
    if (a3act) {
#pragma unroll
        for (int j = 0; j < 8; ++j) {
            int oc = wv_ * 8 + j;
            seq[(long)img * 1283 + oc * 40 + y3 * 8 + x3] = fmaxf(a3[j] + b3[oc], 0.f);
        }
    }
    if (t < 3) seq[(long)img * 1283 + 1280 + t] = relpos[img * 3 + t];
}

// ---------------------------------------------------------------------------
// Sensory synapse sums for all 2048 (b,s) pairs, 4 pairs per block.
// Params as float4 {A,B,WE,W} from global (L2-hot).
// ---------------------------------------------------------------------------
__global__ __launch_bounds__(256) void sensory_kernel(
    const float* __restrict__ sp, const float* __restrict__ seq,
    const float* __restrict__ iw, const float* __restrict__ ibias,
    float* __restrict__ wnum, float* __restrict__ wden) {
    const float4* P4 = (const float4*)sp;
    __shared__ float I[4 * 1283];
    __shared__ float red[4][4][64][2];
    const int t  = threadIdx.x;
    const int pb = blockIdx.x * 4;

    for (int i = t; i < 4 * 1283; i += 256) {
        int p = i / 1283;
        int k = i - p * 1283;
        I[i] = fmaf(seq[(long)pb * 1283 + i], iw[k], ibias[k]);
    }
    __syncthreads();

    const int u = t & 63, kg = t >> 6;
    const bool uval = u < 48;
    float n0 = 0, n1 = 0, n2 = 0, n3 = 0, d0 = 0, d1 = 0, d2 = 0, d3 = 0;
    for (int k = kg; k < 1283; k += 4) {
        float4 pv = P4[k * 64 + u];   // x=A, y=B, z=WE, w=W
        float r0 = __builtin_amdgcn_rcpf(1.f + __builtin_amdgcn_exp2f(fmaf(pv.x, I[k], pv.y)));
        float r1 = __builtin_amdgcn_rcpf(1.f + __builtin_amdgcn_exp2f(fmaf(pv.x, I[1283 + k], pv.y)));
        float r2 = __builtin_amdgcn_rcpf(1.f + __builtin_amdgcn_exp2f(fmaf(pv.x, I[2566 + k], pv.y)));
        float r3 = __builtin_amdgcn_rcpf(1.f + __builtin_amdgcn_exp2f(fmaf(pv.x, I[3849 + k], pv.y)));
        n0 = fmaf(pv.z, r0, n0); d0 = fmaf(pv.w, r0, d0);
        n1 = fmaf(pv.z, r1, n1); d1 = fmaf(pv.w, r1, d1);
        n2 = fmaf(pv.z, r2, n2); d2 = fmaf(pv.w, r2, d2);
        n3 = fmaf(pv.z, r3, n3); d3 = fmaf(pv.w, r3, d3);
    }
    if (uval) {
        red[kg][0][u][0] = n0; red[kg][0][u][1] = d0;
        red[kg][1][u][0] = n1; red[kg][1][u][1] = d1;
        red[kg][2][u][0] = n2; red[kg][2][u][1] = d2;
        red[kg][3][u][0] = n3; red[kg][3][u][1] = d3;
    }
    __syncthreads();
    if (t < 192) {
        int p = t / 48, uu = t - p * 48;
        float n = red[0][p][uu][0] + red[1][p][uu][0] + red[2][p][uu][0] + red[3][p][uu][0];
        float d = red[0][p][uu][1] + red[1][p][uu][1] + red[2][p][uu][1] + red[3][p][uu][1];
        wnum[(long)(pb + p) * 48 + uu] = n;
        wden[(long)(pb + p) * 48 + uu] = d;
    }
}

// ---------------------------------------------------------------------------
// Recurrent LTC scan: one block per batch element; per-lane params cached in
// registers across all 192 unfolds (12 j's x float4 per lane).
// ---------------------------------------------------------------------------
__global__ __launch_bounds__(256) void recurrent_kernel(
    const float* __restrict__ rp, const float* __restrict__ cmglv,
    const float* __restrict__ wnum, const float* __restrict__ wden,
    const float* __restrict__ out_w, const float* __restrict__ out_b,
    const float* __restrict__ head_w, const float* __restrict__ head_b,
    float* __restrict__ outp) {
    const float4* RP4 = (const float4*)rp;
    __shared__ float v[64];
    __shared__ float2 red[4][64];
    __shared__ float ym[4];
    const int t = threadIdx.x, b = blockIdx.x;
    const int u = t & 63, jg = t >> 6;
    const bool uval = u < 48;
    const int j0 = jg * 12;
    float4 rpj[12];
#pragma unroll
    for (int jj = 0; jj < 12; ++jj) rpj[jj] = RP4[(j0 + jj) * 64 + u];
    if (t < 64) v[t] = 0.f;
    float cmt = 0.f, gl = 0.f, glv = 0.f;
    if (uval) { cmt = cmglv[u]; gl = cmglv[64 + u]; glv = cmglv[128 + u]; }
    __syncthreads();

    float yacc = 0.f;
    for (int s = 0; s < 32; ++s) {
        float wn = 0.f, wd = 0.f;
        if (uval) {
            wn = wnum[((long)b * 32 + s) * 48 + u];
            wd = wden[((long)b * 32 + s) * 48 + u];
        }
#pragma unroll 1
        for (int unf = 0; unf < 6; ++unf) {
            float pn = 0.f, pd = 0.f;
#pragma unroll
            for (int jj = 0; jj < 12; ++jj) {
                float vj = v[j0 + jj];
                float r = __builtin_amdgcn_rcpf(1.f + __builtin_amdgcn_exp2f(fmaf(rpj[jj].x, vj, rpj[jj].y)));
                pn = fmaf(rpj[jj].z, r, pn);
                pd = fmaf(rpj[jj].w, r, pd);
            }
            red[jg][u] = make_float2(pn, pd);
            __syncthreads();
            if (jg == 0 && uval) {
                float sn = red[0][u].x + red[1][u].x + red[2][u].x + red[3][u].x;
                float sd = red[0][u].y + red[1][u].y + red[2][u].y + red[3][u].y;
                float num = fmaf(cmt, v[u], glv) + sn + wn;
                float den = cmt + gl + sd + wd;
                v[u] = num / (den + 1e-8f);
            }
            __syncthreads();
        }
        if (t < 4) yacc += v[t] * out_w[t] + out_b[t];
    }
    if (t < 4) ym[t] = yacc;
    __syncthreads();
    if (t < 2) {
        const float inv = 1.f / 32.f;
        float o = ym[0] * inv * head_w[t] + ym[1] * inv * head_w[2 + t] +
                  ym[2] * inv * head_w[4 + t] + ym[3] * inv * head_w[6 + t] + head_b[t];
        outp[b * 2 + t] = tanhf(o);
    }
}

extern "C" void kernel_launch(void* const* d_in, const int* in_sizes, int n_in,
                              void* d_out, int out_size, void* d_ws, size_t ws_size,
                              hipStream_t stream) {
    const float* depth      = (const float*)d_in[0];
    const float* relpos     = (const float*)d_in[1];
    const float* w1         = (const float*)d_in[2];
    const float* b1         = (const float*)d_in[3];
    const float* w2         = (const float*)d_in[4];
    const float* b2         = (const float*)d_in[5];
    const float* w3         = (const float*)d_in[6];
    const float* b3         = (const float*)d_in[7];
    const float* iw         = (const float*)d_in[8];
    const float* ibias      = (const float*)d_in[9];
    const float* sens_w     = (const float*)d_in[10];
    const float* sens_mu    = (const float*)d_in[11];
    const float* sens_sigma = (const float*)d_in[12];
    const float* sens_erev  = (const float*)d_in[13];
    const float* rec_w      = (const float*)d_in[14];
    const float* rec_mu     = (const float*)d_in[15];
    const float* rec_sigma  = (const float*)d_in[16];
    const float* rec_erev   = (const float*)d_in[17];
    const float* gleak      = (const float*)d_in[18];
    const float* vleak      = (const float*)d_in[19];
    const float* cm         = (const float*)d_in[20];
    const float* out_w      = (const float*)d_in[21];
    const float* out_b      = (const float*)d_in[22];
    const float* head_w     = (const float*)d_in[23];
    const float* head_b     = (const float*)d_in[24];
    const int*   sens_mask  = (const int*)d_in[25];
    const int*   rec_mask   = (const int*)d_in[26];

    float* ws = (float*)d_ws;
    float* out = (float*)d_out;

    prep_kernel<<<477, 256, 0, stream>>>(sens_w, sens_mu, sens_sigma, sens_erev, sens_mask,
                                         rec_w, rec_mu, rec_sigma, rec_erev, rec_mask,
                                         gleak, vleak, cm, w2, w3, ws);
    cnn_kernel<<<2048, 256, 0, stream>>>(depth, relpos, w1, b1, b2, b3,
                                         ws + OFF_W2U, ws + OFF_W3U, ws + OFF_SEQ);
    sensory_kernel<<<512, 256, 0, stream>>>(ws + OFF_SP4, ws + OFF_SEQ, iw, ibias,
                                            ws + OFF_WN, ws + OFF_WD);
    recurrent_kernel<<<64, 256, 0, stream>>>(ws + OFF_RP4, ws + OFF_CM, ws + OFF_WN, ws + OFF_WD,
                                             out_w, out_b, head_w, head_b, out);
}

// Round 4
// 390.312 us; speedup vs baseline: 6.3003x; 1.9905x over previous
//
#include <hip/hip_runtime.h>
#include <hip/hip_bf16.h>

// Shapes: B=64 S=32 H=40 W=64 ; conv1: 1->32 (20x32) ; conv2: 32->64 (10x16) ; conv3: 64->32 (5x8)
// SENS=1283 UNITS=48 MOTOR=4 NA=2 UNFOLDS=6

typedef __attribute__((ext_vector_type(8))) short bshort8;   // 8 bf16 (4 VGPR) MFMA frag
typedef __attribute__((ext_vector_type(4))) float f32x4;     // MFMA acc

// ---- workspace layout (float units) ----
constexpr long OFF_SEQ = 0;                 // 2048*1283 = 2627584
constexpr long OFF_SP4 = 2627584;           // sensory params float4[1283*64] = 328448 fl
constexpr long OFF_RP4 = 2956032;           // rec params float4[48*64] = 12288 fl
constexpr long OFF_CM  = 2968320;           // cm_t(64), gl(64), gl*vleak(64)
constexpr long OFF_W2B = 2968512;           // conv2 bf16 frags: 18432 bf16 = 9216 fl
constexpr long OFF_W3B = 2977728;           // conv3 bf16 frags: 18432 bf16 = 9216 fl
constexpr long OFF_WN  = 2986944;           // 2048*48
constexpr long OFF_WD  = 3085248;           // 2048*48 (end 3183552 fl = 12.73 MB)

__device__ __forceinline__ float sp_(float x) {
    return fmaxf(x, 0.f) + log1pf(expf(-fabsf(x)));   // stable softplus
}

// ---------------------------------------------------------------------------
// prep: fold LTC params into float4 {A,B,WE,W}; pack conv2/conv3 weights as
// bf16 MFMA B-fragments.
// w2b flat = ((p*4+wv)*64+l)*8+j : value = w2[oc=wv*16+(l&15)][ic=(l>>4)*8+j][ky=p/3][kx=p%3]
// w3b flat = (((nt*9+p)*2+h)*64+l)*8+j : value = w3[oc=nt*16+(l&15)][ic=h*32+(l>>4)*8+j][p]
// ---------------------------------------------------------------------------
__global__ void prep_kernel(const float* __restrict__ sens_w, const float* __restrict__ sens_mu,
                            const float* __restrict__ sens_sigma, const float* __restrict__ sens_erev,
                            const int* __restrict__ sens_mask,
                            const float* __restrict__ rec_w, const float* __restrict__ rec_mu,
                            const float* __restrict__ rec_sigma, const float* __restrict__ rec_erev,
                            const int* __restrict__ rec_mask,
                            const float* __restrict__ gleak, const float* __restrict__ vleak,
                            const float* __restrict__ cm,
                            const float* __restrict__ w2, const float* __restrict__ w3,
                            float* __restrict__ ws) {
    const float L2E = 1.4426950408889634f;
    int i = blockIdx.x * 256 + threadIdx.x;
    if (i < 82112) {                       // sensory: [k 1283][u 64]
        int k = i >> 6, u = i & 63;
        float4 v = make_float4(0.f, 0.f, 0.f, 0.f);
        if (u < 48) {
            int idx = k * 48 + u;
            float m  = sens_mask[idx] ? 1.f : 0.f;
            float sw = sp_(sens_w[idx]) * m;
            float sg = sens_sigma[idx], mu = sens_mu[idx];
            v = make_float4(-sg * L2E, sg * mu * L2E, sw * sens_erev[idx], sw);
        }
        ((float4*)(ws + OFF_SP4))[i] = v;
    } else if (i < 85184) {                // recurrent: [j 48][u 64]
        int q = i - 82112;
        int j = q >> 6, u = q & 63;
        float4 v = make_float4(0.f, 0.f, 0.f, 0.f);
        if (u < 48) {
            int idx = j * 48 + u;
            float m  = rec_mask[idx] ? 1.f : 0.f;
            float sw = sp_(rec_w[idx]) * m;
            float sg = rec_sigma[idx], mu = rec_mu[idx];
            v = make_float4(-sg * L2E, sg * mu * L2E, sw * rec_erev[idx], sw);
        }
        ((float4*)(ws + OFF_RP4))[q] = v;
    } else if (i < 85232) {
        int u = i - 85184;                 // u < 48
        float g = sp_(gleak[u]);
        ws[OFF_CM + u]       = sp_(cm[u]) * 6.f;
        ws[OFF_CM + 64 + u]  = g;
        ws[OFF_CM + 128 + u] = g * vleak[u];
    } else if (i < 103664) {               // w2b
        int n = i - 85232;
        int j = n & 7, l = (n >> 3) & 63, t2 = n >> 9;
        int wv = t2 & 3, p = t2 >> 2;
        int ky = p / 3, kx = p % 3;
        int oc = wv * 16 + (l & 15);
        int ic = (l >> 4) * 8 + j;
        ((__hip_bfloat16*)(ws + OFF_W2B))[n] =
            __float2bfloat16(w2[((oc * 32 + ic) * 3 + ky) * 3 + kx]);
    } else if (i < 122096) {               // w3b
        int n = i - 103664;
        int j = n & 7, l = (n >> 3) & 63, t3 = n >> 9;
        int h = t3 & 1, u2 = t3 >> 1;
        int nt = u2 / 9, p = u2 % 9;
        int ky = p / 3, kx = p % 3;
        int oc = nt * 16 + (l & 15);
        int ic = h * 32 + (l >> 4) * 8 + j;
        ((__hip_bfloat16*)(ws + OFF_W3B))[n] =
            __float2bfloat16(w3[((oc * 64 + ic) * 3 + ky) * 3 + kx]);
    }
}

// ---------------------------------------------------------------------------
// Fused CNN with bf16 MFMA for conv2/conv3. One block per image.
// LDS byte map (51108 B -> 3 blocks/CU):
//  phase A: img bf16 [41 rows][66 cols] @0 (5412 B)   (col = x+2, cols 0 unused/pad)
//           c1e bf16 [q4][21 row][17 x][8 ic] @5412   (22848 B)  x1 even: xe = x1/2
//           c1o same @28260                            (22848 B)  x1 odd:  xo = (x1+1)/2
//  phase C overlay: a2e bf16 [q8][11 row][9 x][8 ic] @0 (12672 B), a2o @12672
// MFMA frags (16x16x32 bf16, verified layouts): A[m=lane&15][k=(lane>>4)*8+j],
// B[k][n=lane&15], C/D col=lane&15 row=(lane>>4)*4+reg.
// ---------------------------------------------------------------------------
#define IMGB 0
#define C1E  5412
#define C1O  28260
#define A2E  0
#define A2O  12672
#define SMB  51120

__global__ __launch_bounds__(256, 3) void cnn_kernel(
    const float* __restrict__ depth, const float* __restrict__ relpos,
    const float* __restrict__ w1, const float* __restrict__ b1,
    const float* __restrict__ b2, const float* __restrict__ b3,
    const __hip_bfloat16* __restrict__ w2b, const __hip_bfloat16* __restrict__ w3b,
    float* __restrict__ seq) {
    __shared__ __align__(16) char smraw[SMB];
    const int t = threadIdx.x;
    const int img = blockIdx.x;
    const int l = t & 63;
    const int wvu = __builtin_amdgcn_readfirstlane(t >> 6);  // wave id, SGPR
    const int m = l & 15, kg = l >> 4;

    // --- preload conv2 B-fragments (9 pos x 4 VGPR) while LDS work proceeds ---
    bshort8 Bf[9];
#pragma unroll
    for (int p = 0; p < 9; ++p)
        Bf[p] = *(const bshort8*)(w2b + ((p * 4 + wvu) * 64 + l) * 8);

    // --- zero entire LDS (img pads + c1 pads) ---
    for (int i = t; i < 12777; i += 256) ((uint*)smraw)[i] = 0u;
    __syncthreads();
    // --- stage image fp32 -> bf16 pairs ---
    for (int i = t; i < 1280; i += 256) {
        int pos = 2 * i;
        int h = pos >> 6, w = pos & 63;   // w even
        float2 d = *(const float2*)(depth + (long)img * 2560 + pos);
        __hip_bfloat162 pk = __float22bfloat162_rn(d);
        *(__hip_bfloat162*)(smraw + IMGB + ((h + 1) * 66 + (w + 2)) * 2) = pk;
    }
    __syncthreads();

    // --- conv1 (fp32 VALU, uniform weights) -> c1 bf16 quad-major parity-split ---
    const __hip_bfloat16* imgp = (const __hip_bfloat16*)(smraw + IMGB);
#pragma unroll 1
    for (int pp = 0; pp < 3; ++pp) {
        int p = t + (pp << 8);
        if (p < 640) {
            int y1 = p >> 5, x1 = p & 31;
            float xin[9];
#pragma unroll
            for (int ky = 0; ky < 3; ++ky)
#pragma unroll
                for (int kx = 0; kx < 3; ++kx)
                    xin[ky * 3 + kx] = __bfloat162float(imgp[(2 * y1 + ky) * 66 + 2 * x1 + kx + 1]);
            int row = y1 + 1;
            int odd = x1 & 1;
            int xi = odd ? ((x1 + 1) >> 1) : (x1 >> 1);
            char* cb = smraw + (odd ? C1O : C1E);
#pragma unroll
            for (int q = 0; q < 4; ++q) {
#pragma unroll
                for (int pr = 0; pr < 4; ++pr) {
                    int oc0 = q * 8 + pr * 2;
                    float a0 = b1[oc0], a1 = b1[oc0 + 1];
#pragma unroll
                    for (int k = 0; k < 9; ++k) {
                        a0 = fmaf(w1[oc0 * 9 + k], xin[k], a0);
                        a1 = fmaf(w1[(oc0 + 1) * 9 + k], xin[k], a1);
                    }
                    __hip_bfloat162 pk = __float22bfloat162_rn(make_float2(fmaxf(a0, 0.f), fmaxf(a1, 0.f)));
                    *(__hip_bfloat162*)(cb + (((q * 21 + row) * 17 + xi) * 8 + pr * 2) * 2) = pk;
                }
            }
        }
    }
    __syncthreads();

    // --- conv2: 10 M-tiles (output rows) x wave's 16 oc, K = 9 pos x 32 ic ---
    f32x4 acc[10];
    {
        float bias = b2[wvu * 16 + m];
#pragma unroll
        for (int mt = 0; mt < 10; ++mt) acc[mt] = (f32x4){bias, bias, bias, bias};
    }
#pragma unroll
    for (int ky = 0; ky < 3; ++ky) {
#pragma unroll
        for (int kx = 0; kx < 3; ++kx) {
            const char* arr = smraw + ((kx == 1) ? C1E : C1O);
            int xi = m + (kx == 2);
            const char* base = arr + ((kg * 21 + ky) * 17 + xi) * 16;
            bshort8 Bp = Bf[ky * 3 + kx];
#pragma unroll
            for (int mt = 0; mt < 10; ++mt) {
                bshort8 A = *(const bshort8*)(base + mt * 544);   // row += 2 per tile
                acc[mt] = __builtin_amdgcn_mfma_f32_16x16x32_bf16(A, Bp, acc[mt], 0, 0, 0);
            }
        }
    }
    __syncthreads();

    // --- a2 overlay: zero (incl pads), then write relu(acc) as bf16 ---
    for (int i = t; i < 6336; i += 256) ((uint*)smraw)[i] = 0u;
    __syncthreads();
    {
        int oc = wvu * 16 + m;
        int q = oc >> 3, sub = oc & 7;
#pragma unroll
        for (int mt = 0; mt < 10; ++mt) {
            int row = mt + 1;
#pragma unroll
            for (int reg = 0; reg < 4; ++reg) {
                int x2 = kg * 4 + reg;
                int odd = x2 & 1;
                int xi = odd ? ((x2 + 1) >> 1) : (x2 >> 1);
                char* ab = smraw + (odd ? A2O : A2E);
                float v = fmaxf(acc[mt][reg], 0.f);
                *(__hip_bfloat16*)(ab + (((q * 11 + row) * 9 + xi) * 8 + sub) * 2) = __float2bfloat16(v);
            }
        }
    }
    __syncthreads();

    // --- conv3: N-tile nt = wv&1; waves 0,1 do M-tiles {0,2}, waves 2,3 do {1} ---
    {
        const int nt = wvu & 1;
        const bool two = wvu < 2;
        f32x4 c3a = (f32x4){0.f, 0.f, 0.f, 0.f};
        f32x4 c3b = (f32x4){0.f, 0.f, 0.f, 0.f};
        const int xb = m & 7, yb = m >> 3;
#pragma unroll
        for (int p = 0; p < 9; ++p) {
            int ky = p / 3, kx = p % 3;
            const char* arr = smraw + ((kx == 1) ? A2E : A2O);
            int xi3 = xb + (kx == 2);
#pragma unroll
            for (int h = 0; h < 2; ++h) {
                bshort8 B = *(const bshort8*)(w3b + (((nt * 9 + p) * 2 + h) * 64 + l) * 8);
                int q = h * 4 + kg;
                const char* base = arr + ((q * 11 + 2 * yb + ky) * 9 + xi3) * 16;
                if (two) {
                    bshort8 A0 = *(const bshort8*)(base);            // tile 0
                    c3a = __builtin_amdgcn_mfma_f32_16x16x32_bf16(A0, B, c3a, 0, 0, 0);
                    bshort8 A2 = *(const bshort8*)(base + 1152);     // tile 2 (row+8)
                    c3b = __builtin_amdgcn_mfma_f32_16x16x32_bf16(A2, B, c3b, 0, 0, 0);
                } else {
                    bshort8 A1 = *(const bshort8*)(base + 576);      // tile 1 (row+4)
                    c3a = __builtin_amdgcn_mfma_f32_16x16x32_bf16(A1, B, c3a, 0, 0, 0);
                }
            }
        }
        int oc = nt * 16 + m;
        float bv = b3[oc];
        float* so = seq + (long)img * 1283 + oc * 40;
        if (two) {
#pragma unroll
            for (int reg = 0; reg < 4; ++reg) {
                int px0 = kg * 4 + reg;                 // tile 0: px 0..15
                so[px0] = fmaxf(c3a[reg] + bv, 0.f);
                int px2 = 32 + kg * 4 + reg;            // tile 2: px 32..39 valid
                if (px2 < 40) so[px2] = fmaxf(c3b[reg] + bv, 0.f);
            }
        } else {
#pragma unroll
            for (int reg = 0; reg < 4; ++reg) {
                int px1 = 16 + kg * 4 + reg;            // tile 1: px 16..31
                so[px1] = fmaxf(c3a[reg] + bv, 0.f);
            }
        }
    }
    if (t < 3) seq[(long)img * 1283 + 1280 + t] = relpos[img * 3 + t];
}

// ---------------------------------------------------------------------------
// Sensory synapse sums for all 2048 (b,s) pairs, 4 pairs per block.
// ---------------------------------------------------------------------------
__global__ __launch_bounds__(256) void sensory_kernel(
    const float* __restrict__ sp, const float* __restrict__ seq,
    const float* __restrict__ iw, const float* __restrict__ ibias,
    float* __restrict__ wnum, float* __restrict__ wden) {
    const float4* P4 = (const float4*)sp;
    __shared__ float I[4 * 1283];
    __shared__ float red[4][4][64][2];
    const int t  = threadIdx.x;
    const int pb = blockIdx.x * 4;

    for (int i = t; i < 4 * 1283; i += 256) {
        int p = i / 1283;
        int k = i - p * 1283;
        I[i] = fmaf(seq[(long)pb * 1283 + i], iw[k], ibias[k]);
    }
    __syncthreads();

    const int u = t & 63, kg = t >> 6;
    const bool uval = u < 48;
    float n0 = 0, n1 = 0, n2 = 0, n3 = 0, d0 = 0, d1 = 0, d2 = 0, d3 = 0;
    for (int k = kg; k < 1283; k += 4) {
        float4 pv = P4[k * 64 + u];   // x=A, y=B, z=WE, w=W
        float r0 = __builtin_amdgcn_rcpf(1.f + __builtin_amdgcn_exp2f(fmaf(pv.x, I[k], pv.y)));
        float r1 = __builtin_amdgcn_rcpf(1.f + __builtin_amdgcn_exp2f(fmaf(pv.x, I[1283 + k], pv.y)));
        float r2 = __builtin_amdgcn_rcpf(1.f + __builtin_amdgcn_exp2f(fmaf(pv.x, I[2566 + k], pv.y)));
        float r3 = __builtin_amdgcn_rcpf(1.f + __builtin_amdgcn_exp2f(fmaf(pv.x, I[3849 + k], pv.y)));
        n0 = fmaf(pv.z, r0, n0); d0 = fmaf(pv.w, r0, d0);
        n1 = fmaf(pv.z, r1, n1); d1 = fmaf(pv.w, r1, d1);
        n2 = fmaf(pv.z, r2, n2); d2 = fmaf(pv.w, r2, d2);
        n3 = fmaf(pv.z, r3, n3); d3 = fmaf(pv.w, r3, d3);
    }
    if (uval) {
        red[kg][0][u][0] = n0; red[kg][0][u][1] = d0;
        red[kg][1][u][0] = n1; red[kg][1][u][1] = d1;
        red[kg][2][u][0] = n2; red[kg][2][u][1] = d2;
        red[kg][3][u][0] = n3; red[kg][3][u][1] = d3;
    }
    __syncthreads();
    if (t < 192) {
        int p = t / 48, uu = t - p * 48;
        float n = red[0][p][uu][0] + red[1][p][uu][0] + red[2][p][uu][0] + red[3][p][uu][0];
        float d = red[0][p][uu][1] + red[1][p][uu][1] + red[2][p][uu][1] + red[3][p][uu][1];
        wnum[(long)(pb + p) * 48 + uu] = n;
        wden[(long)(pb + p) * 48 + uu] = d;
    }
}

// ---------------------------------------------------------------------------
// Recurrent LTC scan: one block per batch element; per-lane params in regs.
// ---------------------------------------------------------------------------
__global__ __launch_bounds__(256) void recurrent_kernel(
    const float* __restrict__ rp, const float* __restrict__ cmglv,
    const float* __restrict__ wnum, const float* __restrict__ wden,
    const float* __restrict__ out_w, const float* __restrict__ out_b,
    const float* __restrict__ head_w, const float* __restrict__ head_b,
    float* __restrict__ outp) {
    const float4* RP4 = (const float4*)rp;
    __shared__ float v[64];
    __shared__ float2 red[4][64];
    __shared__ float ym[4];
    const int t = threadIdx.x, b = blockIdx.x;
    const int u = t & 63, jg = t >> 6;
    const bool uval = u < 48;
    const int j0 = jg * 12;
    float4 rpj[12];
#pragma unroll
    for (int jj = 0; jj < 12; ++jj) rpj[jj] = RP4[(j0 + jj) * 64 + u];
    if (t < 64) v[t] = 0.f;
    float cmt = 0.f, gl = 0.f, glv = 0.f;
    if (uval) { cmt = cmglv[u]; gl = cmglv[64 + u]; glv = cmglv[128 + u]; }
    __syncthreads();

    float yacc = 0.f;
    for (int s = 0; s < 32; ++s) {
        float wn = 0.f, wd = 0.f;
        if (uval) {
            wn = wnum[((long)b * 32 + s) * 48 + u];
            wd = wden[((long)b * 32 + s) * 48 + u];
        }
#pragma unroll 1
        for (int unf = 0; unf < 6; ++unf) {
            float pn = 0.f, pd = 0.f;
#pragma unroll
            for (int jj = 0; jj < 12; ++jj) {
                float vj = v[j0 + jj];
                float r = __builtin_amdgcn_rcpf(1.f + __builtin_amdgcn_exp2f(fmaf(rpj[jj].x, vj, rpj[jj].y)));
                pn = fmaf(rpj[jj].z, r, pn);
                pd = fmaf(rpj[jj].w, r, pd);
            }
            red[jg][u] = make_float2(pn, pd);
            __syncthreads();
            if (jg == 0 && uval) {
                float sn = red[0][u].x + red[1][u].x + red[2][u].x + red[3][u].x;
                float sd = red[0][u].y + red[1][u].y + red[2][u].y + red[3][u].y;
                float num = fmaf(cmt, v[u], glv) + sn + wn;
                float den = cmt + gl + sd + wd;
                v[u] = num / (den + 1e-8f);
            }
            __syncthreads();
        }
        if (t < 4) yacc += v[t] * out_w[t] + out_b[t];
    }
    if (t < 4) ym[t] = yacc;
    __syncthreads();
    if (t < 2) {
        const float inv = 1.f / 32.f;
        float o = ym[0] * inv * head_w[t] + ym[1] * inv * head_w[2 + t] +
                  ym[2] * inv * head_w[4 + t] + ym[3] * inv * head_w[6 + t] + head_b[t];
        outp[b * 2 + t] = tanhf(o);
    }
}

extern "C" void kernel_launch(void* const* d_in, const int* in_sizes, int n_in,
                              void* d_out, int out_size, void* d_ws, size_t ws_size,
                              hipStream_t stream) {
    const float* depth      = (const float*)d_in[0];
    const float* relpos     = (const float*)d_in[1];
    const float* w1         = (const float*)d_in[2];
    const float* b1         = (const float*)d_in[3];
    const float* w2         = (const float*)d_in[4];
    const float* b2         = (const float*)d_in[5];
    const float* w3         = (const float*)d_in[6];
    const float* b3         = (const float*)d_in[7];
    const float* iw         = (const float*)d_in[8];
    const float* ibias      = (const float*)d_in[9];
    const float* sens_w     = (const float*)d_in[10];
    const float* sens_mu    = (const float*)d_in[11];
    const float* sens_sigma = (const float*)d_in[12];
    const float* sens_erev  = (const float*)d_in[13];
    const float* rec_w      = (const float*)d_in[14];
    const float* rec_mu     = (const float*)d_in[15];
    const float* rec_sigma  = (const float*)d_in[16];
    const float* rec_erev   = (const float*)d_in[17];
    const float* gleak      = (const float*)d_in[18];
    const float* vleak      = (const float*)d_in[19];
    const float* cm         = (const float*)d_in[20];
    const float* out_w      = (const float*)d_in[21];
    const float* out_b      = (const float*)d_in[22];
    const float* head_w     = (const float*)d_in[23];
    const float* head_b     = (const float*)d_in[24];
    const int*   sens_mask  = (const int*)d_in[25];
    const int*   rec_mask   = (const int*)d_in[26];

    float* ws  = (float*)d_ws;
    float* out = (float*)d_out;

    prep_kernel<<<477, 256, 0, stream>>>(sens_w, sens_mu, sens_sigma, sens_erev, sens_mask,
                                         rec_w, rec_mu, rec_sigma, rec_erev, rec_mask,
                                         gleak, vleak, cm, w2, w3, ws);
    cnn_kernel<<<2048, 256, 0, stream>>>(depth, relpos, w1, b1, b2, b3,
                                         (const __hip_bfloat16*)(ws + OFF_W2B),
                                         (const __hip_bfloat16*)(ws + OFF_W3B),
                                         ws + OFF_SEQ);
    sensory_kernel<<<512, 256, 0, stream>>>(ws + OFF_SP4, ws + OFF_SEQ, iw, ibias,
                                            ws + OFF_WN, ws + OFF_WD);
    recurrent_kernel<<<64, 256, 0, stream>>>(ws + OFF_RP4, ws + OFF_CM, ws + OFF_WN, ws + OFF_WD,
                                             out_w, out_b, head_w, head_b, out);
}

// Round 5
// 361.997 us; speedup vs baseline: 6.7931x; 1.0782x over previous
//
#include <hip/hip_runtime.h>
#include <hip/hip_bf16.h>

// Shapes: B=64 S=32 H=40 W=64 ; conv1: 1->32 (20x32) ; conv2: 32->64 (10x16) ; conv3: 64->32 (5x8)
// SENS=1283 UNITS=48 MOTOR=4 NA=2 UNFOLDS=6

typedef __attribute__((ext_vector_type(8))) short bshort8;   // 8 bf16 (4 VGPR) MFMA frag
typedef __attribute__((ext_vector_type(4))) float f32x4;     // MFMA acc

// ---- workspace layout (float units) ----
constexpr long OFF_SEQ  = 0;                 // 2048*1283 = 2627584
constexpr long OFF_SP4  = 2627584;           // sensory params float4[1283*48] = 246336 fl (packed, no pad)
constexpr long OFF_RP4  = 2873920;           // rec params float4[48*64] = 12288 fl
constexpr long OFF_CM   = 2886208;           // cm_t(64), gl(64), gl*vleak(64)
constexpr long OFF_W2B  = 2886400;           // conv2 bf16 frags: 18432 bf16 = 9216 fl
constexpr long OFF_W3B  = 2895616;           // conv3 bf16 frags: 18432 bf16 = 9216 fl
constexpr long OFF_PART = 2904832;           // float2[2048*48] = 196608 fl (atomic-accumulated)
// end 3101440 fl = 12.41 MB

__device__ __forceinline__ float sp_(float x) {
    return fmaxf(x, 0.f) + log1pf(expf(-fabsf(x)));   // stable softplus
}

// ---------------------------------------------------------------------------
// prep: fold LTC params into float4 {A,B,WE,W} (sigmoid(sg*(x-mu)) =
// rcp(1+exp2(A*x+B))); pack conv2/conv3 bf16 MFMA B-frags; zero PART.
// ---------------------------------------------------------------------------
__global__ void prep_kernel(const float* __restrict__ sens_w, const float* __restrict__ sens_mu,
                            const float* __restrict__ sens_sigma, const float* __restrict__ sens_erev,
                            const int* __restrict__ sens_mask,
                            const float* __restrict__ rec_w, const float* __restrict__ rec_mu,
                            const float* __restrict__ rec_sigma, const float* __restrict__ rec_erev,
                            const int* __restrict__ rec_mask,
                            const float* __restrict__ gleak, const float* __restrict__ vleak,
                            const float* __restrict__ cm,
                            const float* __restrict__ w2, const float* __restrict__ w3,
                            float* __restrict__ ws) {
    const float L2E = 1.4426950408889634f;
    int i = blockIdx.x * 256 + threadIdx.x;
    if (i < 61584) {                       // sensory packed [k 1283][u 48]
        float m  = sens_mask[i] ? 1.f : 0.f;
        float sw = sp_(sens_w[i]) * m;
        float sg = sens_sigma[i], mu = sens_mu[i];
        ((float4*)(ws + OFF_SP4))[i] =
            make_float4(-sg * L2E, sg * mu * L2E, sw * sens_erev[i], sw);
    } else if (i < 64656) {                // recurrent: [j 48][u 64 padded]
        int q = i - 61584;
        int j = q >> 6, u = q & 63;
        float4 v = make_float4(0.f, 0.f, 0.f, 0.f);
        if (u < 48) {
            int idx = j * 48 + u;
            float m  = rec_mask[idx] ? 1.f : 0.f;
            float sw = sp_(rec_w[idx]) * m;
            float sg = rec_sigma[idx], mu = rec_mu[idx];
            v = make_float4(-sg * L2E, sg * mu * L2E, sw * rec_erev[idx], sw);
        }
        ((float4*)(ws + OFF_RP4))[q] = v;
    } else if (i < 64704) {
        int u = i - 64656;                 // u < 48
        float g = sp_(gleak[u]);
        ws[OFF_CM + u]       = sp_(cm[u]) * 6.f;
        ws[OFF_CM + 64 + u]  = g;
        ws[OFF_CM + 128 + u] = g * vleak[u];
    } else if (i < 83136) {                // w2b frags
        int n = i - 64704;
        int j = n & 7, l = (n >> 3) & 63, t2 = n >> 9;
        int wv = t2 & 3, p = t2 >> 2;
        int ky = p / 3, kx = p % 3;
        int oc = wv * 16 + (l & 15);
        int ic = (l >> 4) * 8 + j;
        ((__hip_bfloat16*)(ws + OFF_W2B))[n] =
            __float2bfloat16(w2[((oc * 32 + ic) * 3 + ky) * 3 + kx]);
    } else if (i < 101568) {               // w3b frags
        int n = i - 83136;
        int j = n & 7, l = (n >> 3) & 63, t3 = n >> 9;
        int h = t3 & 1, u2 = t3 >> 1;
        int nt = u2 / 9, p = u2 % 9;
        int ky = p / 3, kx = p % 3;
        int oc = nt * 16 + (l & 15);
        int ic = h * 32 + (l >> 4) * 8 + j;
        ((__hip_bfloat16*)(ws + OFF_W3B))[n] =
            __float2bfloat16(w3[((oc * 64 + ic) * 3 + ky) * 3 + kx]);
    } else if (i < 150720) {               // zero PART (49152 float4)
        ((float4*)(ws + OFF_PART))[i - 101568] = make_float4(0.f, 0.f, 0.f, 0.f);
    }
}

// ---------------------------------------------------------------------------
// Fused CNN with bf16 MFMA for conv2/conv3 (unchanged from R4 except the
// coalesced seq epilogue through LDS).
// ---------------------------------------------------------------------------
#define IMGB 0
#define C1E  5412
#define C1O  28260
#define A2E  0
#define A2O  12672
#define SMB  51120

__global__ __launch_bounds__(256, 3) void cnn_kernel(
    const float* __restrict__ depth, const float* __restrict__ relpos,
    const float* __restrict__ w1, const float* __restrict__ b1,
    const float* __restrict__ b2, const float* __restrict__ b3,
    const __hip_bfloat16* __restrict__ w2b, const __hip_bfloat16* __restrict__ w3b,
    float* __restrict__ seq) {
    __shared__ __align__(16) char smraw[SMB];
    const int t = threadIdx.x;
    const int img = blockIdx.x;
    const int l = t & 63;
    const int wvu = __builtin_amdgcn_readfirstlane(t >> 6);
    const int m = l & 15, kg = l >> 4;

    bshort8 Bf[9];
#pragma unroll
    for (int p = 0; p < 9; ++p)
        Bf[p] = *(const bshort8*)(w2b + ((p * 4 + wvu) * 64 + l) * 8);

    for (int i = t; i < 12777; i += 256) ((uint*)smraw)[i] = 0u;
    __syncthreads();
    for (int i = t; i < 1280; i += 256) {
        int pos = 2 * i;
        int h = pos >> 6, w = pos & 63;
        float2 d = *(const float2*)(depth + (long)img * 2560 + pos);
        __hip_bfloat162 pk = __float22bfloat162_rn(d);
        *(__hip_bfloat162*)(smraw + IMGB + ((h + 1) * 66 + (w + 2)) * 2) = pk;
    }
    __syncthreads();

    const __hip_bfloat16* imgp = (const __hip_bfloat16*)(smraw + IMGB);
#pragma unroll 1
    for (int pp = 0; pp < 3; ++pp) {
        int p = t + (pp << 8);
        if (p < 640) {
            int y1 = p >> 5, x1 = p & 31;
            float xin[9];
#pragma unroll
            for (int ky = 0; ky < 3; ++ky)
#pragma unroll
                for (int kx = 0; kx < 3; ++kx)
                    xin[ky * 3 + kx] = __bfloat162float(imgp[(2 * y1 + ky) * 66 + 2 * x1 + kx + 1]);
            int row = y1 + 1;
            int odd = x1 & 1;
            int xi = odd ? ((x1 + 1) >> 1) : (x1 >> 1);
            char* cb = smraw + (odd ? C1O : C1E);
#pragma unroll
            for (int q = 0; q < 4; ++q) {
#pragma unroll
                for (int pr = 0; pr < 4; ++pr) {
                    int oc0 = q * 8 + pr * 2;
                    float a0 = b1[oc0], a1 = b1[oc0 + 1];
#pragma unroll
                    for (int k = 0; k < 9; ++k) {
                        a0 = fmaf(w1[oc0 * 9 + k], xin[k], a0);
                        a1 = fmaf(w1[(oc0 + 1) * 9 + k], xin[k], a1);
                    }
                    __hip_bfloat162 pk = __float22bfloat162_rn(make_float2(fmaxf(a0, 0.f), fmaxf(a1, 0.f)));
                    *(__hip_bfloat162*)(cb + (((q * 21 + row) * 17 + xi) * 8 + pr * 2) * 2) = pk;
                }
            }
        }
    }
    __syncthreads();

    f32x4 acc[10];
    {
        float bias = b2[wvu * 16 + m];
#pragma unroll
        for (int mt = 0; mt < 10; ++mt) acc[mt] = (f32x4){bias, bias, bias, bias};
    }
#pragma unroll
    for (int ky = 0; ky < 3; ++ky) {
#pragma unroll
        for (int kx = 0; kx < 3; ++kx) {
            const char* arr = smraw + ((kx == 1) ? C1E : C1O);
            int xi = m + (kx == 2);
            const char* base = arr + ((kg * 21 + ky) * 17 + xi) * 16;
            bshort8 Bp = Bf[ky * 3 + kx];
#pragma unroll
            for (int mt = 0; mt < 10; ++mt) {
                bshort8 A = *(const bshort8*)(base + mt * 544);
                acc[mt] = __builtin_amdgcn_mfma_f32_16x16x32_bf16(A, Bp, acc[mt], 0, 0, 0);
            }
        }
    }
    __syncthreads();

    for (int i = t; i < 6336; i += 256) ((uint*)smraw)[i] = 0u;
    __syncthreads();
    {
        int oc = wvu * 16 + m;
        int q = oc >> 3, sub = oc & 7;
#pragma unroll
        for (int mt = 0; mt < 10; ++mt) {
            int row = mt + 1;
#pragma unroll
            for (int reg = 0; reg < 4; ++reg) {
                int x2 = kg * 4 + reg;
                int odd = x2 & 1;
                int xi = odd ? ((x2 + 1) >> 1) : (x2 >> 1);
                char* ab = smraw + (odd ? A2O : A2E);
                float v = fmaxf(acc[mt][reg], 0.f);
                *(__hip_bfloat16*)(ab + (((q * 11 + row) * 9 + xi) * 8 + sub) * 2) = __float2bfloat16(v);
            }
        }
    }
    __syncthreads();

    {
        const int nt = wvu & 1;
        const bool two = wvu < 2;
        f32x4 c3a = (f32x4){0.f, 0.f, 0.f, 0.f};
        f32x4 c3b = (f32x4){0.f, 0.f, 0.f, 0.f};
        const int xb = m & 7, yb = m >> 3;
#pragma unroll
        for (int p = 0; p < 9; ++p) {
            int ky = p / 3, kx = p % 3;
            const char* arr = smraw + ((kx == 1) ? A2E : A2O);
            int xi3 = xb + (kx == 2);
#pragma unroll
            for (int h = 0; h < 2; ++h) {
                bshort8 B = *(const bshort8*)(w3b + (((nt * 9 + p) * 2 + h) * 64 + l) * 8);
                int q = h * 4 + kg;
                const char* base = arr + ((q * 11 + 2 * yb + ky) * 9 + xi3) * 16;
                if (two) {
                    bshort8 A0 = *(const bshort8*)(base);
                    c3a = __builtin_amdgcn_mfma_f32_16x16x32_bf16(A0, B, c3a, 0, 0, 0);
                    bshort8 A2 = *(const bshort8*)(base + 1152);
                    c3b = __builtin_amdgcn_mfma_f32_16x16x32_bf16(A2, B, c3b, 0, 0, 0);
                } else {
                    bshort8 A1 = *(const bshort8*)(base + 576);
                    c3a = __builtin_amdgcn_mfma_f32_16x16x32_bf16(A1, B, c3a, 0, 0, 0);
                }
            }
        }
        __syncthreads();                         // all a2 reads done; reuse LDS as seq stage
        float* sb = (float*)smraw;               // 1280 floats
        int oc = nt * 16 + m;
        float bv = b3[oc];
        int ob40 = oc * 40;
        if (two) {
#pragma unroll
            for (int reg = 0; reg < 4; ++reg) {
                sb[ob40 + kg * 4 + reg] = fmaxf(c3a[reg] + bv, 0.f);
                int px2 = 32 + kg * 4 + reg;
                if (px2 < 40) sb[ob40 + px2] = fmaxf(c3b[reg] + bv, 0.f);
            }
        } else {
#pragma unroll
            for (int reg = 0; reg < 4; ++reg)
                sb[ob40 + 16 + kg * 4 + reg] = fmaxf(c3a[reg] + bv, 0.f);
        }
        __syncthreads();
        for (int i = t; i < 1283; i += 256)
            seq[(long)img * 1283 + i] = (i < 1280) ? sb[i] : relpos[img * 3 + (i - 1280)];
    }
}

// ---------------------------------------------------------------------------
// Sensory synapse sums: grid (512 pairgroups, 2 k-halves) x 192 threads.
// Thread = (kg = t/48 in 0..3, u = t%48). Packed params [k][48] float4.
// Partials accumulated into PART via atomicAdd (2 deterministic addends).
// ---------------------------------------------------------------------------
__global__ __launch_bounds__(192) void sensory_kernel(
    const float* __restrict__ sp, const float* __restrict__ seq,
    const float* __restrict__ iw, const float* __restrict__ ibias,
    float2* __restrict__ part) {
    const float4* P4 = (const float4*)sp;
    __shared__ __align__(16) float ITf[642 * 4];     // [kk][4 pairs]
    __shared__ float2 red[4][4][48];                  // [kg][p][u]
    const int t  = threadIdx.x;
    const int pb = blockIdx.x * 4;
    const int kbase = blockIdx.y * 642;
    const int klen  = blockIdx.y ? 641 : 642;

    for (int i = t; i < klen * 4; i += 192) {
        int kk = i >> 2, p = i & 3;
        int k = kbase + kk;
        ITf[i] = fmaf(seq[(long)(pb + p) * 1283 + k], iw[k], ibias[k]);
    }
    __syncthreads();

    const int kg = t / 48, u = t - kg * 48;
    float n0 = 0, n1 = 0, n2 = 0, n3 = 0, d0 = 0, d1 = 0, d2 = 0, d3 = 0;
#pragma unroll 1
    for (int i = 0; i < 81; ++i) {
#pragma unroll
        for (int e = 0; e < 2; ++e) {
            int klc = i * 8 + kg * 2 + e;
            if (klc < klen) {
                float4 pv = P4[(long)(kbase + klc) * 48 + u];   // {A,B,WE,W}
                float4 Iv = *(const float4*)&ITf[klc * 4];
                float r0 = __builtin_amdgcn_rcpf(1.f + __builtin_amdgcn_exp2f(fmaf(pv.x, Iv.x, pv.y)));
                float r1 = __builtin_amdgcn_rcpf(1.f + __builtin_amdgcn_exp2f(fmaf(pv.x, Iv.y, pv.y)));
                float r2 = __builtin_amdgcn_rcpf(1.f + __builtin_amdgcn_exp2f(fmaf(pv.x, Iv.z, pv.y)));
                float r3 = __builtin_amdgcn_rcpf(1.f + __builtin_amdgcn_exp2f(fmaf(pv.x, Iv.w, pv.y)));
                n0 = fmaf(pv.z, r0, n0); d0 = fmaf(pv.w, r0, d0);
                n1 = fmaf(pv.z, r1, n1); d1 = fmaf(pv.w, r1, d1);
                n2 = fmaf(pv.z, r2, n2); d2 = fmaf(pv.w, r2, d2);
                n3 = fmaf(pv.z, r3, n3); d3 = fmaf(pv.w, r3, d3);
            }
        }
    }
    red[kg][0][u] = make_float2(n0, d0);
    red[kg][1][u] = make_float2(n1, d1);
    red[kg][2][u] = make_float2(n2, d2);
    red[kg][3][u] = make_float2(n3, d3);
    __syncthreads();
    {
        int p = t / 48, uu = t - p * 48;
        float2 a = red[0][p][uu], b = red[1][p][uu], c = red[2][p][uu], d = red[3][p][uu];
        float n = a.x + b.x + c.x + d.x;
        float dd = a.y + b.y + c.y + d.y;
        float2* dst = part + (long)(pb + p) * 48 + uu;
        atomicAdd(&dst->x, n);
        atomicAdd(&dst->y, dd);
    }
}

// ---------------------------------------------------------------------------
// Recurrent LTC scan: one block (512 thr, 8 waves) per batch element.
// v lives in registers (all waves hold full v lane-wise); 1 barrier/unfold
// via double-buffered partial array; wn/wd prefetched to LDS.
// ---------------------------------------------------------------------------
__global__ __launch_bounds__(512) void recurrent_kernel(
    const float* __restrict__ rp, const float* __restrict__ cmglv,
    const float2* __restrict__ part,
    const float* __restrict__ out_w, const float* __restrict__ out_b,
    const float* __restrict__ head_w, const float* __restrict__ head_b,
    float* __restrict__ outp) {
    const float4* RP4 = (const float4*)rp;
    __shared__ float2 WL[32 * 48];      // [s][u]
    __shared__ float2 red[2][8][64];    // double-buffered [jg][u]
    __shared__ float ym[4];
    const int t = threadIdx.x, b = blockIdx.x;
    const int u = t & 63;
    const int jg = __builtin_amdgcn_readfirstlane(t >> 6);   // 0..7
    const int j0 = jg * 6;
    const bool uval = u < 48;
    float4 rpj[6];
#pragma unroll
    for (int jj = 0; jj < 6; ++jj) rpj[jj] = RP4[(j0 + jj) * 64 + u];
    for (int i = t; i < 1536; i += 512) WL[i] = part[(long)b * 1536 + i];
    float cmt = 0.f, gl = 0.f, glv = 0.f;
    if (uval) { cmt = cmglv[u]; gl = cmglv[64 + u]; glv = cmglv[128 + u]; }
    float ow = 0.f, ob = 0.f;
    if (jg == 0 && u < 4) { ow = out_w[u]; ob = out_b[u]; }
    __syncthreads();

    float vn = 0.f;
    float yacc = 0.f;
    int buf = 0;
    for (int s = 0; s < 32; ++s) {
        float2 wnd = uval ? WL[s * 48 + u] : make_float2(0.f, 0.f);
#pragma unroll 1
        for (int unf = 0; unf < 6; ++unf) {
            float pn = 0.f, pd = 0.f;
#pragma unroll
            for (int jj = 0; jj < 6; ++jj) {
                float vj = __shfl(vn, j0 + jj, 64);
                float r = __builtin_amdgcn_rcpf(1.f + __builtin_amdgcn_exp2f(fmaf(rpj[jj].x, vj, rpj[jj].y)));
                pn = fmaf(rpj[jj].z, r, pn);
                pd = fmaf(rpj[jj].w, r, pd);
            }
            red[buf][jg][u] = make_float2(pn, pd);
            __syncthreads();
            float sn = 0.f, sd = 0.f;
#pragma unroll
            for (int g = 0; g < 8; ++g) {
                float2 rr = red[buf][g][u];
                sn += rr.x; sd += rr.y;
            }
            float num = fmaf(cmt, vn, glv) + sn + wnd.x;
            float den = cmt + gl + sd + wnd.y;
            vn = uval ? num / (den + 1e-8f) : 0.f;
            buf ^= 1;
        }
        if (jg == 0 && u < 4) yacc = fmaf(vn, ow, yacc) + ob;
    }
    if (jg == 0 && u < 4) ym[u] = yacc;
    __syncthreads();
    if (t < 2) {
        const float inv = 1.f / 32.f;
        float o = ym[0] * inv * head_w[t] + ym[1] * inv * head_w[2 + t] +
                  ym[2] * inv * head_w[4 + t] + ym[3] * inv * head_w[6 + t] + head_b[t];
        outp[b * 2 + t] = tanhf(o);
    }
}

extern "C" void kernel_launch(void* const* d_in, const int* in_sizes, int n_in,
                              void* d_out, int out_size, void* d_ws, size_t ws_size,
                              hipStream_t stream) {
    const float* depth      = (const float*)d_in[0];
    const float* relpos     = (const float*)d_in[1];
    const float* w1         = (const float*)d_in[2];
    const float* b1         = (const float*)d_in[3];
    const float* w2         = (const float*)d_in[4];
    const float* b2         = (const float*)d_in[5];
    const float* w3         = (const float*)d_in[6];
    const float* b3         = (const float*)d_in[7];
    const float* iw         = (const float*)d_in[8];
    const float* ibias      = (const float*)d_in[9];
    const float* sens_w     = (const float*)d_in[10];
    const float* sens_mu    = (const float*)d_in[11];
    const float* sens_sigma = (const float*)d_in[12];
    const float* sens_erev  = (const float*)d_in[13];
    const float* rec_w      = (const float*)d_in[14];
    const float* rec_mu     = (const float*)d_in[15];
    const float* rec_sigma  = (const float*)d_in[16];
    const float* rec_erev   = (const float*)d_in[17];
    const float* gleak      = (const float*)d_in[18];
    const float* vleak      = (const float*)d_in[19];
    const float* cm         = (const float*)d_in[20];
    const float* out_w      = (const float*)d_in[21];
    const float* out_b      = (const float*)d_in[22];
    const float* head_w     = (const float*)d_in[23];
    const float* head_b     = (const float*)d_in[24];
    const int*   sens_mask  = (const int*)d_in[25];
    const int*   rec_mask   = (const int*)d_in[26];

    float* ws  = (float*)d_ws;
    float* out = (float*)d_out;

    prep_kernel<<<589, 256, 0, stream>>>(sens_w, sens_mu, sens_sigma, sens_erev, sens_mask,
                                         rec_w, rec_mu, rec_sigma, rec_erev, rec_mask,
                                         gleak, vleak, cm, w2, w3, ws);
    cnn_kernel<<<2048, 256, 0, stream>>>(depth, relpos, w1, b1, b2, b3,
                                         (const __hip_bfloat16*)(ws + OFF_W2B),
                                         (const __hip_bfloat16*)(ws + OFF_W3B),
                                         ws + OFF_SEQ);
    sensory_kernel<<<dim3(512, 2), 192, 0, stream>>>(ws + OFF_SP4, ws + OFF_SEQ, iw, ibias,
                                                     (float2*)(ws + OFF_PART));
    recurrent_kernel<<<64, 512, 0, stream>>>(ws + OFF_RP4, ws + OFF_CM,
                                             (const float2*)(ws + OFF_PART),
                                             out_w, out_b, head_w, head_b, out);
}

// Round 7
// 346.086 us; speedup vs baseline: 7.1054x; 1.0460x over previous
//
#include <hip/hip_runtime.h>
#include <hip/hip_bf16.h>

// Shapes: B=64 S=32 H=40 W=64 ; conv1: 1->32 (20x32) ; conv2: 32->64 (10x16) ; conv3: 64->32 (5x8)
// SENS=1283 UNITS=48 MOTOR=4 NA=2 UNFOLDS=6

typedef __attribute__((ext_vector_type(8))) short bshort8;   // 8 bf16 (4 VGPR) MFMA frag
typedef __attribute__((ext_vector_type(4))) float f32x4;     // MFMA acc

// ---- workspace layout (float units) ----
constexpr long OFF_SEQ  = 0;                 // 2048*1283 = 2627584
constexpr long OFF_SP4  = 2627584;           // sensory params float4[1283*48] = 246336 fl
constexpr long OFF_RP4  = 2873920;           // rec params float4[48*64] = 12288 fl
constexpr long OFF_CM   = 2886208;           // cm_t(64), gl(64), gl*vleak(64)
constexpr long OFF_W2B  = 2886400;           // conv2 bf16 frags: 18432 bf16 = 9216 fl
constexpr long OFF_W3B  = 2895616;           // conv3 bf16 frags: 18432 bf16 = 9216 fl
constexpr long OFF_PART = 2904832;           // float2[2048*48] = 196608 fl (written whole by sensory)
// end 3101440 fl = 12.41 MB

__device__ __forceinline__ float sp_(float x) {
    return fmaxf(x, 0.f) + log1pf(expf(-fabsf(x)));   // stable softplus
}

// ---------------------------------------------------------------------------
// prep: fold LTC params into float4 {A,B,WE,W} (sigmoid(sg*(x-mu)) =
// rcp(1+exp2(A*x+B))); pack conv2/conv3 bf16 MFMA B-frags.
// ---------------------------------------------------------------------------
__global__ void prep_kernel(const float* __restrict__ sens_w, const float* __restrict__ sens_mu,
                            const float* __restrict__ sens_sigma, const float* __restrict__ sens_erev,
                            const int* __restrict__ sens_mask,
                            const float* __restrict__ rec_w, const float* __restrict__ rec_mu,
                            const float* __restrict__ rec_sigma, const float* __restrict__ rec_erev,
                            const int* __restrict__ rec_mask,
                            const float* __restrict__ gleak, const float* __restrict__ vleak,
                            const float* __restrict__ cm,
                            const float* __restrict__ w2, const float* __restrict__ w3,
                            float* __restrict__ ws) {
    const float L2E = 1.4426950408889634f;
    int i = blockIdx.x * 256 + threadIdx.x;
    if (i < 61584) {                       // sensory packed [k 1283][u 48]
        float m  = sens_mask[i] ? 1.f : 0.f;
        float sw = sp_(sens_w[i]) * m;
        float sg = sens_sigma[i], mu = sens_mu[i];
        ((float4*)(ws + OFF_SP4))[i] =
            make_float4(-sg * L2E, sg * mu * L2E, sw * sens_erev[i], sw);
    } else if (i < 64656) {                // recurrent: [j 48][u 64 padded]
        int q = i - 61584;
        int j = q >> 6, u = q & 63;
        float4 v = make_float4(0.f, 0.f, 0.f, 0.f);
        if (u < 48) {
            int idx = j * 48 + u;
            float m  = rec_mask[idx] ? 1.f : 0.f;
            float sw = sp_(rec_w[idx]) * m;
            float sg = rec_sigma[idx], mu = rec_mu[idx];
            v = make_float4(-sg * L2E, sg * mu * L2E, sw * rec_erev[idx], sw);
        }
        ((float4*)(ws + OFF_RP4))[q] = v;
    } else if (i < 64704) {
        int u = i - 64656;                 // u < 48
        float g = sp_(gleak[u]);
        ws[OFF_CM + u]       = sp_(cm[u]) * 6.f;
        ws[OFF_CM + 64 + u]  = g;
        ws[OFF_CM + 128 + u] = g * vleak[u];
    } else if (i < 83136) {                // w2b frags
        int n = i - 64704;
        int j = n & 7, l = (n >> 3) & 63, t2 = n >> 9;
        int wv = t2 & 3, p = t2 >> 2;
        int ky = p / 3, kx = p % 3;
        int oc = wv * 16 + (l & 15);
        int ic = (l >> 4) * 8 + j;
        ((__hip_bfloat16*)(ws + OFF_W2B))[n] =
            __float2bfloat16(w2[((oc * 32 + ic) * 3 + ky) * 3 + kx]);
    } else if (i < 101568) {               // w3b frags
        int n = i - 83136;
        int j = n & 7, l = (n >> 3) & 63, t3 = n >> 9;
        int h = t3 & 1, u2 = t3 >> 1;
        int nt = u2 / 9, p = u2 % 9;
        int ky = p / 3, kx = p % 3;
        int oc = nt * 16 + (l & 15);
        int ic = h * 32 + (l >> 4) * 8 + j;
        ((__hip_bfloat16*)(ws + OFF_W3B))[n] =
            __float2bfloat16(w3[((oc * 64 + ic) * 3 + ky) * 3 + kx]);
    }
}

// ---------------------------------------------------------------------------
// Fused CNN with bf16 MFMA for conv2/conv3 — R5-verbatim (known good).
// LDS byte map (51108 B -> 3 blocks/CU):
//  phase A: img bf16 [41 rows][66 cols] @0 | c1e [4q][21r][17x][8ic] @5412 |
//           c1o same @28260
//  phase C overlay: a2e [8q][11][9][8] @0, a2o @12672; then seq stage @0.
// ---------------------------------------------------------------------------
#define IMGB 0
#define C1E  5412
#define C1O  28260
#define A2E  0
#define A2O  12672
#define SMB  51120

__global__ __launch_bounds__(256, 3) void cnn_kernel(
    const float* __restrict__ depth, const float* __restrict__ relpos,
    const float* __restrict__ w1, const float* __restrict__ b1,
    const float* __restrict__ b2, const float* __restrict__ b3,
    const __hip_bfloat16* __restrict__ w2b, const __hip_bfloat16* __restrict__ w3b,
    float* __restrict__ seq) {
    __shared__ __align__(16) char smraw[SMB];
    const int t = threadIdx.x;
    const int img = blockIdx.x;
    const int l = t & 63;
    const int wvu = __builtin_amdgcn_readfirstlane(t >> 6);
    const int m = l & 15, kg = l >> 4;

    bshort8 Bf[9];
#pragma unroll
    for (int p = 0; p < 9; ++p)
        Bf[p] = *(const bshort8*)(w2b + ((p * 4 + wvu) * 64 + l) * 8);

    for (int i = t; i < 12777; i += 256) ((uint*)smraw)[i] = 0u;
    __syncthreads();
    for (int i = t; i < 1280; i += 256) {
        int pos = 2 * i;
        int h = pos >> 6, w = pos & 63;
        float2 d = *(const float2*)(depth + (long)img * 2560 + pos);
        __hip_bfloat162 pk = __float22bfloat162_rn(d);
        *(__hip_bfloat162*)(smraw + IMGB + ((h + 1) * 66 + (w + 2)) * 2) = pk;
    }
    __syncthreads();

    const __hip_bfloat16* imgp = (const __hip_bfloat16*)(smraw + IMGB);
#pragma unroll 1
    for (int pp = 0; pp < 3; ++pp) {
        int p = t + (pp << 8);
        if (p < 640) {
            int y1 = p >> 5, x1 = p & 31;
            float xin[9];
#pragma unroll
            for (int ky = 0; ky < 3; ++ky)
#pragma unroll
                for (int kx = 0; kx < 3; ++kx)
                    xin[ky * 3 + kx] = __bfloat162float(imgp[(2 * y1 + ky) * 66 + 2 * x1 + kx + 1]);
            int row = y1 + 1;
            int odd = x1 & 1;
            int xi = odd ? ((x1 + 1) >> 1) : (x1 >> 1);
            char* cb = smraw + (odd ? C1O : C1E);
#pragma unroll
            for (int q = 0; q < 4; ++q) {
#pragma unroll
                for (int pr = 0; pr < 4; ++pr) {
                    int oc0 = q * 8 + pr * 2;
                    float a0 = b1[oc0], a1 = b1[oc0 + 1];
#pragma unroll
                    for (int k = 0; k < 9; ++k) {
                        a0 = fmaf(w1[oc0 * 9 + k], xin[k], a0);
                        a1 = fmaf(w1[(oc0 + 1) * 9 + k], xin[k], a1);
                    }
                    __hip_bfloat162 pk = __float22bfloat162_rn(make_float2(fmaxf(a0, 0.f), fmaxf(a1, 0.f)));
                    *(__hip_bfloat162*)(cb + (((q * 21 + row) * 17 + xi) * 8 + pr * 2) * 2) = pk;
                }
            }
        }
    }
    __syncthreads();

    f32x4 acc[10];
    {
        float bias = b2[wvu * 16 + m];
#pragma unroll
        for (int mt = 0; mt < 10; ++mt) acc[mt] = (f32x4){bias, bias, bias, bias};
    }
#pragma unroll
    for (int ky = 0; ky < 3; ++ky) {
#pragma unroll
        for (int kx = 0; kx < 3; ++kx) {
            const char* arr = smraw + ((kx == 1) ? C1E : C1O);
            int xi = m + (kx == 2);
            const char* base = arr + ((kg * 21 + ky) * 17 + xi) * 16;
            bshort8 Bp = Bf[ky * 3 + kx];
#pragma unroll
            for (int mt = 0; mt < 10; ++mt) {
                bshort8 A = *(const bshort8*)(base + mt * 544);
                acc[mt] = __builtin_amdgcn_mfma_f32_16x16x32_bf16(A, Bp, acc[mt], 0, 0, 0);
            }
        }
    }
    __syncthreads();

    for (int i = t; i < 6336; i += 256) ((uint*)smraw)[i] = 0u;
    __syncthreads();
    {
        int oc = wvu * 16 + m;
        int q = oc >> 3, sub = oc & 7;
#pragma unroll
        for (int mt = 0; mt < 10; ++mt) {
            int row = mt + 1;
#pragma unroll
            for (int reg = 0; reg < 4; ++reg) {
                int x2 = kg * 4 + reg;
                int odd = x2 & 1;
                int xi = odd ? ((x2 + 1) >> 1) : (x2 >> 1);
                char* ab = smraw + (odd ? A2O : A2E);
                float v = fmaxf(acc[mt][reg], 0.f);
                *(__hip_bfloat16*)(ab + (((q * 11 + row) * 9 + xi) * 8 + sub) * 2) = __float2bfloat16(v);
            }
        }
    }
    __syncthreads();

    {
        const int nt = wvu & 1;
        const bool two = wvu < 2;
        f32x4 c3a = (f32x4){0.f, 0.f, 0.f, 0.f};
        f32x4 c3b = (f32x4){0.f, 0.f, 0.f, 0.f};
        const int xb = m & 7, yb = m >> 3;
#pragma unroll
        for (int p = 0; p < 9; ++p) {
            int ky = p / 3, kx = p % 3;
            const char* arr = smraw + ((kx == 1) ? A2E : A2O);
            int xi3 = xb + (kx == 2);
#pragma unroll
            for (int h = 0; h < 2; ++h) {
                bshort8 B = *(const bshort8*)(w3b + (((nt * 9 + p) * 2 + h) * 64 + l) * 8);
                int q = h * 4 + kg;
                const char* base = arr + ((q * 11 + 2 * yb + ky) * 9 + xi3) * 16;
                if (two) {
                    bshort8 A0 = *(const bshort8*)(base);
                    c3a = __builtin_amdgcn_mfma_f32_16x16x32_bf16(A0, B, c3a, 0, 0, 0);
                    bshort8 A2 = *(const bshort8*)(base + 1152);
                    c3b = __builtin_amdgcn_mfma_f32_16x16x32_bf16(A2, B, c3b, 0, 0, 0);
                } else {
                    bshort8 A1 = *(const bshort8*)(base + 576);
                    c3a = __builtin_amdgcn_mfma_f32_16x16x32_bf16(A1, B, c3a, 0, 0, 0);
                }
            }
        }
        __syncthreads();
        float* sb = (float*)smraw;
        int oc = nt * 16 + m;
        float bv = b3[oc];
        int ob40 = oc * 40;
        if (two) {
#pragma unroll
            for (int reg = 0; reg < 4; ++reg) {
                sb[ob40 + kg * 4 + reg] = fmaxf(c3a[reg] + bv, 0.f);
                int px2 = 32 + kg * 4 + reg;
                if (px2 < 40) sb[ob40 + px2] = fmaxf(c3b[reg] + bv, 0.f);
            }
        } else {
#pragma unroll
            for (int reg = 0; reg < 4; ++reg)
                sb[ob40 + 16 + kg * 4 + reg] = fmaxf(c3a[reg] + bv, 0.f);
        }
        __syncthreads();
        for (int i = t; i < 1283; i += 256)
            seq[(long)img * 1283 + i] = (i < 1280) ? sb[i] : relpos[img * 3 + (i - 1280)];
    }
}

// ---------------------------------------------------------------------------
// Sensory synapse sums, pair-blocked: 256 blocks x 768 threads; each block
// owns 8 pairs, streams the 985 KB param array once (252 MB total).
// LDS: single 48 KB buffer, time-shared: IT [1283][8] floats (41056 B) during
// the k-loop, then (after a barrier) red [16][8][48] float2 (49152 B).
// ---------------------------------------------------------------------------
__global__ __launch_bounds__(768) void sensory_kernel(
    const float* __restrict__ sp, const float* __restrict__ seq,
    const float* __restrict__ iw, const float* __restrict__ ibias,
    float2* __restrict__ part) {
    const float4* P4 = (const float4*)sp;
    __shared__ __align__(16) char sbuf[49152];
    float*  IT  = (float*)sbuf;        // [k][8 pairs]
    float2* red = (float2*)sbuf;       // [(kg*8+p)*48+u], valid after mid-barrier
    const int t = threadIdx.x;
    const int pb = blockIdx.x * 8;

    for (int p = 0; p < 8; ++p)
        for (int k = t; k < 1283; k += 768)
            IT[k * 8 + p] = fmaf(seq[(long)(pb + p) * 1283 + k], iw[k], ibias[k]);
    __syncthreads();

    const int u = t % 48, kg = t / 48;   // kg in 0..15
    float2 acc[8];
#pragma unroll
    for (int p = 0; p < 8; ++p) acc[p] = make_float2(0.f, 0.f);

#pragma unroll 2
    for (int i = 0; i < 81; ++i) {
        int k = kg + 16 * i;
        if (k < 1283) {
            float4 pv = P4[k * 48 + u];          // {A,B,WE,W}
            float4 Ia = *(const float4*)&IT[k * 8];
            float4 Ib = *(const float4*)&IT[k * 8 + 4];
            float r0 = __builtin_amdgcn_rcpf(1.f + __builtin_amdgcn_exp2f(fmaf(pv.x, Ia.x, pv.y)));
            float r1 = __builtin_amdgcn_rcpf(1.f + __builtin_amdgcn_exp2f(fmaf(pv.x, Ia.y, pv.y)));
            float r2 = __builtin_amdgcn_rcpf(1.f + __builtin_amdgcn_exp2f(fmaf(pv.x, Ia.z, pv.y)));
            float r3 = __builtin_amdgcn_rcpf(1.f + __builtin_amdgcn_exp2f(fmaf(pv.x, Ia.w, pv.y)));
            float r4 = __builtin_amdgcn_rcpf(1.f + __builtin_amdgcn_exp2f(fmaf(pv.x, Ib.x, pv.y)));
            float r5 = __builtin_amdgcn_rcpf(1.f + __builtin_amdgcn_exp2f(fmaf(pv.x, Ib.y, pv.y)));
            float r6 = __builtin_amdgcn_rcpf(1.f + __builtin_amdgcn_exp2f(fmaf(pv.x, Ib.z, pv.y)));
            float r7 = __builtin_amdgcn_rcpf(1.f + __builtin_amdgcn_exp2f(fmaf(pv.x, Ib.w, pv.y)));
            acc[0].x = fmaf(pv.z, r0, acc[0].x); acc[0].y = fmaf(pv.w, r0, acc[0].y);
            acc[1].x = fmaf(pv.z, r1, acc[1].x); acc[1].y = fmaf(pv.w, r1, acc[1].y);
            acc[2].x = fmaf(pv.z, r2, acc[2].x); acc[2].y = fmaf(pv.w, r2, acc[2].y);
            acc[3].x = fmaf(pv.z, r3, acc[3].x); acc[3].y = fmaf(pv.w, r3, acc[3].y);
            acc[4].x = fmaf(pv.z, r4, acc[4].x); acc[4].y = fmaf(pv.w, r4, acc[4].y);
            acc[5].x = fmaf(pv.z, r5, acc[5].x); acc[5].y = fmaf(pv.w, r5, acc[5].y);
            acc[6].x = fmaf(pv.z, r6, acc[6].x); acc[6].y = fmaf(pv.w, r6, acc[6].y);
            acc[7].x = fmaf(pv.z, r7, acc[7].x); acc[7].y = fmaf(pv.w, r7, acc[7].y);
        }
    }
    __syncthreads();                    // IT reads done; sbuf becomes red
#pragma unroll
    for (int p = 0; p < 8; ++p) red[(kg * 8 + p) * 48 + u] = acc[p];
    __syncthreads();
    if (t < 384) {
        int p = t / 48, uu = t - p * 48;
        float sn = 0.f, sd = 0.f;
#pragma unroll
        for (int g = 0; g < 16; ++g) {
            float2 rr = red[(g * 8 + p) * 48 + uu];
            sn += rr.x; sd += rr.y;
        }
        part[(long)(pb + p) * 48 + uu] = make_float2(sn, sd);
    }
}

// ---------------------------------------------------------------------------
// Recurrent LTC scan: one block (512 thr, 8 waves) per batch element.
// v in registers (lane-wise, broadcast via shfl); 1 barrier/unfold.
// ---------------------------------------------------------------------------
__global__ __launch_bounds__(512) void recurrent_kernel(
    const float* __restrict__ rp, const float* __restrict__ cmglv,
    const float2* __restrict__ part,
    const float* __restrict__ out_w, const float* __restrict__ out_b,
    const float* __restrict__ head_w, const float* __restrict__ head_b,
    float* __restrict__ outp) {
    const float4* RP4 = (const float4*)rp;
    __shared__ float2 WL[32 * 48];
    __shared__ float2 red[2][8][64];
    __shared__ float ym[4];
    const int t = threadIdx.x, b = blockIdx.x;
    const int u = t & 63;
    const int jg = __builtin_amdgcn_readfirstlane(t >> 6);
    const int j0 = jg * 6;
    const bool uval = u < 48;
    float4 rpj[6];
#pragma unroll
    for (int jj = 0; jj < 6; ++jj) rpj[jj] = RP4[(j0 + jj) * 64 + u];
    for (int i = t; i < 1536; i += 512) WL[i] = part[(long)b * 1536 + i];
    float cmt = 0.f, gl = 0.f, glv = 0.f;
    if (uval) { cmt = cmglv[u]; gl = cmglv[64 + u]; glv = cmglv[128 + u]; }
    float ow = 0.f, ob = 0.f;
    if (jg == 0 && u < 4) { ow = out_w[u]; ob = out_b[u]; }
    __syncthreads();

    float vn = 0.f;
    float yacc = 0.f;
    int buf = 0;
    for (int s = 0; s < 32; ++s) {
        float2 wnd = uval ? WL[s * 48 + u] : make_float2(0.f, 0.f);
#pragma unroll 1
        for (int unf = 0; unf < 6; ++unf) {
            float pn = 0.f, pd = 0.f;
#pragma unroll
            for (int jj = 0; jj < 6; ++jj) {
                float vj = __shfl(vn, j0 + jj, 64);
                float r = __builtin_amdgcn_rcpf(1.f + __builtin_amdgcn_exp2f(fmaf(rpj[jj].x, vj, rpj[jj].y)));
                pn = fmaf(rpj[jj].z, r, pn);
                pd = fmaf(rpj[jj].w, r, pd);
            }
            red[buf][jg][u] = make_float2(pn, pd);
            __syncthreads();
            float sn = 0.f, sd = 0.f;
#pragma unroll
            for (int g = 0; g < 8; ++g) {
                float2 rr = red[buf][g][u];
                sn += rr.x; sd += rr.y;
            }
            float num = fmaf(cmt, vn, glv) + sn + wnd.x;
            float den = cmt + gl + sd + wnd.y;
            vn = uval ? num / (den + 1e-8f) : 0.f;
            buf ^= 1;
        }
        if (jg == 0 && u < 4) yacc = fmaf(vn, ow, yacc) + ob;
    }
    if (jg == 0 && u < 4) ym[u] = yacc;
    __syncthreads();
    if (t < 2) {
        const float inv = 1.f / 32.f;
        float o = ym[0] * inv * head_w[t] + ym[1] * inv * head_w[2 + t] +
                  ym[2] * inv * head_w[4 + t] + ym[3] * inv * head_w[6 + t] + head_b[t];
        outp[b * 2 + t] = tanhf(o);
    }
}

extern "C" void kernel_launch(void* const* d_in, const int* in_sizes, int n_in,
                              void* d_out, int out_size, void* d_ws, size_t ws_size,
                              hipStream_t stream) {
    const float* depth      = (const float*)d_in[0];
    const float* relpos     = (const float*)d_in[1];
    const float* w1         = (const float*)d_in[2];
    const float* b1         = (const float*)d_in[3];
    const float* w2         = (const float*)d_in[4];
    const float* b2         = (const float*)d_in[5];
    const float* w3         = (const float*)d_in[6];
    const float* b3         = (const float*)d_in[7];
    const float* iw         = (const float*)d_in[8];
    const float* ibias      = (const float*)d_in[9];
    const float* sens_w     = (const float*)d_in[10];
    const float* sens_mu    = (const float*)d_in[11];
    const float* sens_sigma = (const float*)d_in[12];
    const float* sens_erev  = (const float*)d_in[13];
    const float* rec_w      = (const float*)d_in[14];
    const float* rec_mu     = (const float*)d_in[15];
    const float* rec_sigma  = (const float*)d_in[16];
    const float* rec_erev   = (const float*)d_in[17];
    const float* gleak      = (const float*)d_in[18];
    const float* vleak      = (const float*)d_in[19];
    const float* cm         = (const float*)d_in[20];
    const float* out_w      = (const float*)d_in[21];
    const float* out_b      = (const float*)d_in[22];
    const float* head_w     = (const float*)d_in[23];
    const float* head_b     = (const float*)d_in[24];
    const int*   sens_mask  = (const int*)d_in[25];
    const int*   rec_mask   = (const int*)d_in[26];

    float* ws  = (float*)d_ws;
    float* out = (float*)d_out;

    prep_kernel<<<477, 256, 0, stream>>>(sens_w, sens_mu, sens_sigma, sens_erev, sens_mask,
                                         rec_w, rec_mu, rec_sigma, rec_erev, rec_mask,
                                         gleak, vleak, cm, w2, w3, ws);
    cnn_kernel<<<2048, 256, 0, stream>>>(depth, relpos, w1, b1, b2, b3,
                                         (const __hip_bfloat16*)(ws + OFF_W2B),
                                         (const __hip_bfloat16*)(ws + OFF_W3B),
                                         ws + OFF_SEQ);
    sensory_kernel<<<256, 768, 0, stream>>>(ws + OFF_SP4, ws + OFF_SEQ, iw, ibias,
                                            (float2*)(ws + OFF_PART));
    recurrent_kernel<<<64, 512, 0, stream>>>(ws + OFF_RP4, ws + OFF_CM,
                                             (const float2*)(ws + OFF_PART),
                                             out_w, out_b, head_w, head_b, out);
}

// Round 9
// 341.509 us; speedup vs baseline: 7.2007x; 1.0134x over previous
//
#include <hip/hip_runtime.h>
#include <hip/hip_bf16.h>

// Shapes: B=64 S=32 H=40 W=64 ; conv1: 1->32 (20x32) ; conv2: 32->64 (10x16) ; conv3: 64->32 (5x8)
// SENS=1283 UNITS=48 MOTOR=4 NA=2 UNFOLDS=6

typedef __attribute__((ext_vector_type(8))) short bshort8;   // 8 bf16 (4 VGPR) MFMA frag
typedef __attribute__((ext_vector_type(4))) float f32x4;     // MFMA acc

// ---- workspace layout (float units) ----
constexpr long OFF_SEQ  = 0;                 // 2048*1283 = 2627584
constexpr long OFF_SP4  = 2627584;           // sensory params float4[1283*48] = 246336 fl
constexpr long OFF_RP4  = 2873920;           // rec params float4[48*64] = 12288 fl
constexpr long OFF_CM   = 2886208;           // cm_t(64), gl(64), gl*vleak(64)
constexpr long OFF_W2B  = 2886400;           // conv2 bf16 frags: 18432 bf16 = 9216 fl
constexpr long OFF_W3B  = 2895616;           // conv3 bf16 frags: 18432 bf16 = 9216 fl
constexpr long OFF_PART = 2904832;           // float2[2048*48] = 196608 fl
// end 3101440 fl = 12.41 MB

__device__ __forceinline__ float sp_(float x) {
    return fmaxf(x, 0.f) + log1pf(expf(-fabsf(x)));   // stable softplus
}

// ---------------------------------------------------------------------------
// prep (R7-verbatim)
// ---------------------------------------------------------------------------
__global__ void prep_kernel(const float* __restrict__ sens_w, const float* __restrict__ sens_mu,
                            const float* __restrict__ sens_sigma, const float* __restrict__ sens_erev,
                            const int* __restrict__ sens_mask,
                            const float* __restrict__ rec_w, const float* __restrict__ rec_mu,
                            const float* __restrict__ rec_sigma, const float* __restrict__ rec_erev,
                            const int* __restrict__ rec_mask,
                            const float* __restrict__ gleak, const float* __restrict__ vleak,
                            const float* __restrict__ cm,
                            const float* __restrict__ w2, const float* __restrict__ w3,
                            float* __restrict__ ws) {
    const float L2E = 1.4426950408889634f;
    int i = blockIdx.x * 256 + threadIdx.x;
    if (i < 61584) {                       // sensory packed [k 1283][u 48]
        float m  = sens_mask[i] ? 1.f : 0.f;
        float sw = sp_(sens_w[i]) * m;
        float sg = sens_sigma[i], mu = sens_mu[i];
        ((float4*)(ws + OFF_SP4))[i] =
            make_float4(-sg * L2E, sg * mu * L2E, sw * sens_erev[i], sw);
    } else if (i < 64656) {                // recurrent: [j 48][u 64 padded]
        int q = i - 61584;
        int j = q >> 6, u = q & 63;
        float4 v = make_float4(0.f, 0.f, 0.f, 0.f);
        if (u < 48) {
            int idx = j * 48 + u;
            float m  = rec_mask[idx] ? 1.f : 0.f;
            float sw = sp_(rec_w[idx]) * m;
            float sg = rec_sigma[idx], mu = rec_mu[idx];
            v = make_float4(-sg * L2E, sg * mu * L2E, sw * rec_erev[idx], sw);
        }
        ((float4*)(ws + OFF_RP4))[q] = v;
    } else if (i < 64704) {
        int u = i - 64656;                 // u < 48
        float g = sp_(gleak[u]);
        ws[OFF_CM + u]       = sp_(cm[u]) * 6.f;
        ws[OFF_CM + 64 + u]  = g;
        ws[OFF_CM + 128 + u] = g * vleak[u];
    } else if (i < 83136) {                // w2b frags
        int n = i - 64704;
        int j = n & 7, l = (n >> 3) & 63, t2 = n >> 9;
        int wv = t2 & 3, p = t2 >> 2;
        int ky = p / 3, kx = p % 3;
        int oc = wv * 16 + (l & 15);
        int ic = (l >> 4) * 8 + j;
        ((__hip_bfloat16*)(ws + OFF_W2B))[n] =
            __float2bfloat16(w2[((oc * 32 + ic) * 3 + ky) * 3 + kx]);
    } else if (i < 101568) {               // w3b frags
        int n = i - 83136;
        int j = n & 7, l = (n >> 3) & 63, t3 = n >> 9;
        int h = t3 & 1, u2 = t3 >> 1;
        int nt = u2 / 9, p = u2 % 9;
        int ky = p / 3, kx = p % 3;
        int oc = nt * 16 + (l & 15);
        int ic = h * 32 + (l >> 4) * 8 + j;
        ((__hip_bfloat16*)(ws + OFF_W3B))[n] =
            __float2bfloat16(w3[((oc * 64 + ic) * 3 + ky) * 3 + kx]);
    }
}

// ---------------------------------------------------------------------------
// Fused CNN — R7-verbatim structure (full zeroing, 8 barriers, identical LDS
// layout and conv2/conv3) with ONLY conv1 swapped: wave owns 4 oc x 2 passes,
// 36 weights + 4 biases hoisted into uniform locals (SGPR-resident), 10 px
// per lane exactly. Bitwise-identical c1 values to R7.
// ---------------------------------------------------------------------------
#define IMGB 0
#define C1E  5412
#define C1O  28260
#define A2E  0
#define A2O  12672
#define SMB  51120

__global__ __launch_bounds__(256, 3) void cnn_kernel(
    const float* __restrict__ depth, const float* __restrict__ relpos,
    const float* __restrict__ w1, const float* __restrict__ b1,
    const float* __restrict__ b2, const float* __restrict__ b3,
    const __hip_bfloat16* __restrict__ w2b, const __hip_bfloat16* __restrict__ w3b,
    float* __restrict__ seq) {
    __shared__ __align__(16) char smraw[SMB];
    const int t = threadIdx.x;
    const int img = blockIdx.x;
    const int l = t & 63;
    const int wvu = __builtin_amdgcn_readfirstlane(t >> 6);
    const int m = l & 15, kg = l >> 4;

    bshort8 Bf[9];
#pragma unroll
    for (int p = 0; p < 9; ++p)
        Bf[p] = *(const bshort8*)(w2b + ((p * 4 + wvu) * 64 + l) * 8);

    for (int i = t; i < 12777; i += 256) ((uint*)smraw)[i] = 0u;
    __syncthreads();
    for (int i = t; i < 1280; i += 256) {
        int pos = 2 * i;
        int h = pos >> 6, w = pos & 63;
        float2 d = *(const float2*)(depth + (long)img * 2560 + pos);
        __hip_bfloat162 pk = __float22bfloat162_rn(d);
        *(__hip_bfloat162*)(smraw + IMGB + ((h + 1) * 66 + (w + 2)) * 2) = pk;
    }
    __syncthreads();

    // ---- conv1 (REWORKED): wave wvu -> oc groups {wvu, wvu+4}, 10 px/lane ----
    const __hip_bfloat16* imgp = (const __hip_bfloat16*)(smraw + IMGB);
#pragma unroll 1
    for (int pc = 0; pc < 2; ++pc) {
        const int g = wvu + 4 * pc;          // uniform 0..7: oc = g*4 .. g*4+3
        const int q1 = g >> 1;               // channel quad
        const int sub = (g & 1) * 4;         // element base within quad
        float wv[4][9], bv[4];               // uniform loads, hoisted
#pragma unroll
        for (int j = 0; j < 4; ++j) {
            bv[j] = b1[g * 4 + j];
#pragma unroll
            for (int k = 0; k < 9; ++k) wv[j][k] = w1[(g * 4 + j) * 9 + k];
        }
#pragma unroll 1
        for (int i = 0; i < 10; ++i) {
            int p = l + (i << 6);            // 0..639, each px once per wave
            int y1 = p >> 5, x1 = p & 31;
            float xin[9];
#pragma unroll
            for (int ky = 0; ky < 3; ++ky)
#pragma unroll
                for (int kx = 0; kx < 3; ++kx)
                    xin[ky * 3 + kx] = __bfloat162float(imgp[(2 * y1 + ky) * 66 + 2 * x1 + kx + 1]);
            float o[4];
#pragma unroll
            for (int j = 0; j < 4; ++j) {
                float a = bv[j];
#pragma unroll
                for (int k = 0; k < 9; ++k) a = fmaf(wv[j][k], xin[k], a);
                o[j] = fmaxf(a, 0.f);
            }
            int odd = x1 & 1;
            int xi = odd ? ((x1 + 1) >> 1) : (x1 >> 1);
            char* cb = smraw + (odd ? C1O : C1E) +
                       (((q1 * 21 + (y1 + 1)) * 17 + xi) * 8 + sub) * 2;
            *(__hip_bfloat162*)cb       = __float22bfloat162_rn(make_float2(o[0], o[1]));
            *(__hip_bfloat162*)(cb + 4) = __float22bfloat162_rn(make_float2(o[2], o[3]));
        }
    }
    __syncthreads();

    // ---- conv2 (R7-verbatim): 10 M-tiles x wave's 16 oc ----
    f32x4 acc[10];
    {
        float bias = b2[wvu * 16 + m];
#pragma unroll
        for (int mt = 0; mt < 10; ++mt) acc[mt] = (f32x4){bias, bias, bias, bias};
    }
#pragma unroll
    for (int ky = 0; ky < 3; ++ky) {
#pragma unroll
        for (int kx = 0; kx < 3; ++kx) {
            const char* arr = smraw + ((kx == 1) ? C1E : C1O);
            int xi = m + (kx == 2);
            const char* base = arr + ((kg * 21 + ky) * 17 + xi) * 16;
            bshort8 Bp = Bf[ky * 3 + kx];
#pragma unroll
            for (int mt = 0; mt < 10; ++mt) {
                bshort8 A = *(const bshort8*)(base + mt * 544);
                acc[mt] = __builtin_amdgcn_mfma_f32_16x16x32_bf16(A, Bp, acc[mt], 0, 0, 0);
            }
        }
    }
    __syncthreads();

    for (int i = t; i < 6336; i += 256) ((uint*)smraw)[i] = 0u;
    __syncthreads();
    {
        int oc = wvu * 16 + m;
        int q = oc >> 3, sub = oc & 7;
#pragma unroll
        for (int mt = 0; mt < 10; ++mt) {
            int row = mt + 1;
#pragma unroll
            for (int reg = 0; reg < 4; ++reg) {
                int x2 = kg * 4 + reg;
                int odd = x2 & 1;
                int xi = odd ? ((x2 + 1) >> 1) : (x2 >> 1);
                char* ab = smraw + (odd ? A2O : A2E);
                float v = fmaxf(acc[mt][reg], 0.f);
                *(__hip_bfloat16*)(ab + (((q * 11 + row) * 9 + xi) * 8 + sub) * 2) = __float2bfloat16(v);
            }
        }
    }
    __syncthreads();

    {
        const int nt = wvu & 1;
        const bool two = wvu < 2;
        f32x4 c3a = (f32x4){0.f, 0.f, 0.f, 0.f};
        f32x4 c3b = (f32x4){0.f, 0.f, 0.f, 0.f};
        const int xb = m & 7, yb = m >> 3;
#pragma unroll
        for (int p = 0; p < 9; ++p) {
            int ky = p / 3, kx = p % 3;
            const char* arr = smraw + ((kx == 1) ? A2E : A2O);
            int xi3 = xb + (kx == 2);
#pragma unroll
            for (int h = 0; h < 2; ++h) {
                bshort8 B = *(const bshort8*)(w3b + (((nt * 9 + p) * 2 + h) * 64 + l) * 8);
                int q = h * 4 + kg;
                const char* base = arr + ((q * 11 + 2 * yb + ky) * 9 + xi3) * 16;
                if (two) {
                    bshort8 A0 = *(const bshort8*)(base);
                    c3a = __builtin_amdgcn_mfma_f32_16x16x32_bf16(A0, B, c3a, 0, 0, 0);
                    bshort8 A2 = *(const bshort8*)(base + 1152);
                    c3b = __builtin_amdgcn_mfma_f32_16x16x32_bf16(A2, B, c3b, 0, 0, 0);
                } else {
                    bshort8 A1 = *(const bshort8*)(base + 576);
                    c3a = __builtin_amdgcn_mfma_f32_16x16x32_bf16(A1, B, c3a, 0, 0, 0);
                }
            }
        }
        __syncthreads();
        float* sb = (float*)smraw;
        int oc = nt * 16 + m;
        float bv = b3[oc];
        int ob40 = oc * 40;
        if (two) {
#pragma unroll
            for (int reg = 0; reg < 4; ++reg) {
                sb[ob40 + kg * 4 + reg] = fmaxf(c3a[reg] + bv, 0.f);
                int px2 = 32 + kg * 4 + reg;
                if (px2 < 40) sb[ob40 + px2] = fmaxf(c3b[reg] + bv, 0.f);
            }
        } else {
#pragma unroll
            for (int reg = 0; reg < 4; ++reg)
                sb[ob40 + 16 + kg * 4 + reg] = fmaxf(c3a[reg] + bv, 0.f);
        }
        __syncthreads();
        for (int i = t; i < 1283; i += 256)
            seq[(long)img * 1283 + i] = (i < 1280) ? sb[i] : relpos[img * 3 + (i - 1280)];
    }
}

// ---------------------------------------------------------------------------
// Sensory (R7-verbatim): pair-blocked, 256 blocks x 768 thr, 48KB time-shared LDS.
// ---------------------------------------------------------------------------
__global__ __launch_bounds__(768) void sensory_kernel(
    const float* __restrict__ sp, const float* __restrict__ seq,
    const float* __restrict__ iw, const float* __restrict__ ibias,
    float2* __restrict__ part) {
    const float4* P4 = (const float4*)sp;
    __shared__ __align__(16) char sbuf[49152];
    float*  IT  = (float*)sbuf;
    float2* red = (float2*)sbuf;
    const int t = threadIdx.x;
    const int pb = blockIdx.x * 8;

    for (int p = 0; p < 8; ++p)
        for (int k = t; k < 1283; k += 768)
            IT[k * 8 + p] = fmaf(seq[(long)(pb + p) * 1283 + k], iw[k], ibias[k]);
    __syncthreads();

    const int u = t % 48, kg = t / 48;
    float2 acc[8];
#pragma unroll
    for (int p = 0; p < 8; ++p) acc[p] = make_float2(0.f, 0.f);

#pragma unroll 2
    for (int i = 0; i < 81; ++i) {
        int k = kg + 16 * i;
        if (k < 1283) {
            float4 pv = P4[k * 48 + u];
            float4 Ia = *(const float4*)&IT[k * 8];
            float4 Ib = *(const float4*)&IT[k * 8 + 4];
            float r0 = __builtin_amdgcn_rcpf(1.f + __builtin_amdgcn_exp2f(fmaf(pv.x, Ia.x, pv.y)));
            float r1 = __builtin_amdgcn_rcpf(1.f + __builtin_amdgcn_exp2f(fmaf(pv.x, Ia.y, pv.y)));
            float r2 = __builtin_amdgcn_rcpf(1.f + __builtin_amdgcn_exp2f(fmaf(pv.x, Ia.z, pv.y)));
            float r3 = __builtin_amdgcn_rcpf(1.f + __builtin_amdgcn_exp2f(fmaf(pv.x, Ia.w, pv.y)));
            float r4 = __builtin_amdgcn_rcpf(1.f + __builtin_amdgcn_exp2f(fmaf(pv.x, Ib.x, pv.y)));
            float r5 = __builtin_amdgcn_rcpf(1.f + __builtin_amdgcn_exp2f(fmaf(pv.x, Ib.y, pv.y)));
            float r6 = __builtin_amdgcn_rcpf(1.f + __builtin_amdgcn_exp2f(fmaf(pv.x, Ib.z, pv.y)));
            float r7 = __builtin_amdgcn_rcpf(1.f + __builtin_amdgcn_exp2f(fmaf(pv.x, Ib.w, pv.y)));
            acc[0].x = fmaf(pv.z, r0, acc[0].x); acc[0].y = fmaf(pv.w, r0, acc[0].y);
            acc[1].x = fmaf(pv.z, r1, acc[1].x); acc[1].y = fmaf(pv.w, r1, acc[1].y);
            acc[2].x = fmaf(pv.z, r2, acc[2].x); acc[2].y = fmaf(pv.w, r2, acc[2].y);
            acc[3].x = fmaf(pv.z, r3, acc[3].x); acc[3].y = fmaf(pv.w, r3, acc[3].y);
            acc[4].x = fmaf(pv.z, r4, acc[4].x); acc[4].y = fmaf(pv.w, r4, acc[4].y);
            acc[5].x = fmaf(pv.z, r5, acc[5].x); acc[5].y = fmaf(pv.w, r5, acc[5].y);
            acc[6].x = fmaf(pv.z, r6, acc[6].x); acc[6].y = fmaf(pv.w, r6, acc[6].y);
            acc[7].x = fmaf(pv.z, r7, acc[7].x); acc[7].y = fmaf(pv.w, r7, acc[7].y);
        }
    }
    __syncthreads();
#pragma unroll
    for (int p = 0; p < 8; ++p) red[(kg * 8 + p) * 48 + u] = acc[p];
    __syncthreads();
    if (t < 384) {
        int p = t / 48, uu = t - p * 48;
        float sn = 0.f, sd = 0.f;
#pragma unroll
        for (int g = 0; g < 16; ++g) {
            float2 rr = red[(g * 8 + p) * 48 + uu];
            sn += rr.x; sd += rr.y;
        }
        part[(long)(pb + p) * 48 + uu] = make_float2(sn, sd);
    }
}

// ---------------------------------------------------------------------------
// Recurrent (R7-verbatim): 64 blocks x 512 thr, v in regs, 1 barrier/unfold.
// ---------------------------------------------------------------------------
__global__ __launch_bounds__(512) void recurrent_kernel(
    const float* __restrict__ rp, const float* __restrict__ cmglv,
    const float2* __restrict__ part,
    const float* __restrict__ out_w, const float* __restrict__ out_b,
    const float* __restrict__ head_w, const float* __restrict__ head_b,
    float* __restrict__ outp) {
    const float4* RP4 = (const float4*)rp;
    __shared__ float2 WL[32 * 48];
    __shared__ float2 red[2][8][64];
    __shared__ float ym[4];
    const int t = threadIdx.x, b = blockIdx.x;
    const int u = t & 63;
    const int jg = __builtin_amdgcn_readfirstlane(t >> 6);
    const int j0 = jg * 6;
    const bool uval = u < 48;
    float4 rpj[6];
#pragma unroll
    for (int jj = 0; jj < 6; ++jj) rpj[jj] = RP4[(j0 + jj) * 64 + u];
    for (int i = t; i < 1536; i += 512) WL[i] = part[(long)b * 1536 + i];
    float cmt = 0.f, gl = 0.f, glv = 0.f;
    if (uval) { cmt = cmglv[u]; gl = cmglv[64 + u]; glv = cmglv[128 + u]; }
    float ow = 0.f, ob = 0.f;
    if (jg == 0 && u < 4) { ow = out_w[u]; ob = out_b[u]; }
    __syncthreads();

    float vn = 0.f;
    float yacc = 0.f;
    int buf = 0;
    for (int s = 0; s < 32; ++s) {
        float2 wnd = uval ? WL[s * 48 + u] : make_float2(0.f, 0.f);
#pragma unroll 1
        for (int unf = 0; unf < 6; ++unf) {
            float pn = 0.f, pd = 0.f;
#pragma unroll
            for (int jj = 0; jj < 6; ++jj) {
                float vj = __shfl(vn, j0 + jj, 64);
                float r = __builtin_amdgcn_rcpf(1.f + __builtin_amdgcn_exp2f(fmaf(rpj[jj].x, vj, rpj[jj].y)));
                pn = fmaf(rpj[jj].z, r, pn);
                pd = fmaf(rpj[jj].w, r, pd);
            }
            red[buf][jg][u] = make_float2(pn, pd);
            __syncthreads();
            float sn = 0.f, sd = 0.f;
#pragma unroll
            for (int g = 0; g < 8; ++g) {
                float2 rr = red[buf][g][u];
                sn += rr.x; sd += rr.y;
            }
            float num = fmaf(cmt, vn, glv) + sn + wnd.x;
            float den = cmt + gl + sd + wnd.y;
            vn = uval ? num / (den + 1e-8f) : 0.f;
            buf ^= 1;
        }
        if (jg == 0 && u < 4) yacc = fmaf(vn, ow, yacc) + ob;
    }
    if (jg == 0 && u < 4) ym[u] = yacc;
    __syncthreads();
    if (t < 2) {
        const float inv = 1.f / 32.f;
        float o = ym[0] * inv * head_w[t] + ym[1] * inv * head_w[2 + t] +
                  ym[2] * inv * head_w[4 + t] + ym[3] * inv * head_w[6 + t] + head_b[t];
        outp[b * 2 + t] = tanhf(o);
    }
}

extern "C" void kernel_launch(void* const* d_in, const int* in_sizes, int n_in,
                              void* d_out, int out_size, void* d_ws, size_t ws_size,
                              hipStream_t stream) {
    const float* depth      = (const float*)d_in[0];
    const float* relpos     = (const float*)d_in[1];
    const float* w1         = (const float*)d_in[2];
    const float* b1         = (const float*)d_in[3];
    const float* w2         = (const float*)d_in[4];
    const float* b2         = (const float*)d_in[5];
    const float* w3         = (const float*)d_in[6];
    const float* b3         = (const float*)d_in[7];
    const float* iw         = (const float*)d_in[8];
    const float* ibias      = (const float*)d_in[9];
    const float* sens_w     = (const float*)d_in[10];
    const float* sens_mu    = (const float*)d_in[11];
    const float* sens_sigma = (const float*)d_in[12];
    const float* sens_erev  = (const float*)d_in[13];
    const float* rec_w      = (const float*)d_in[14];
    const float* rec_mu     = (const float*)d_in[15];
    const float* rec_sigma  = (const float*)d_in[16];
    const float* rec_erev   = (const float*)d_in[17];
    const float* gleak      = (const float*)d_in[18];
    const float* vleak      = (const float*)d_in[19];
    const float* cm         = (const float*)d_in[20];
    const float* out_w      = (const float*)d_in[21];
    const float* out_b      = (const float*)d_in[22];
    const float* head_w     = (const float*)d_in[23];
    const float* head_b     = (const float*)d_in[24];
    const int*   sens_mask  = (const int*)d_in[25];
    const int*   rec_mask   = (const int*)d_in[26];

    float* ws  = (float*)d_ws;
    float* out = (float*)d_out;

    prep_kernel<<<477, 256, 0, stream>>>(sens_w, sens_mu, sens_sigma, sens_erev, sens_mask,
                                         rec_w, rec_mu, rec_sigma, rec_erev, rec_mask,
                                         gleak, vleak, cm, w2, w3, ws);
    cnn_kernel<<<2048, 256, 0, stream>>>(depth, relpos, w1, b1, b2, b3,
                                         (const __hip_bfloat16*)(ws + OFF_W2B),
                                         (const __hip_bfloat16*)(ws + OFF_W3B),
                                         ws + OFF_SEQ);
    sensory_kernel<<<256, 768, 0, stream>>>(ws + OFF_SP4, ws + OFF_SEQ, iw, ibias,
                                            (float2*)(ws + OFF_PART));
    recurrent_kernel<<<64, 512, 0, stream>>>(ws + OFF_RP4, ws + OFF_CM,
                                             (const float2*)(ws + OFF_PART),
                                             out_w, out_b, head_w, head_b, out);
}